// Round 3
// baseline (635.297 us; speedup 1.0000x reference)
//
#include <hip/hip_runtime.h>
#include <math.h>

// MSAPairWeightedAveraging — fp32 compute, bf16 intermediates (round 2: fixed ws offsets).
// Shapes: S=256, N=384, C_M=64, C_Z=128, C=32, H=8, H*C=256.
// v/g/go are [S,N,256] = 25,165,824 elems each (NOT 6,291,456 — that was the round-0/1 bug).
// ws layout: bl fp32 [8,384,384] | mterm fp32 [384] | v bf16 | g bf16 | go bf16  = 155.7 MB

#define SS 256
#define NN 384
#define CM 64
#define CZ 128
#define CCc 32
#define HH 8
#define HC 256
#define NV 25165824   // S*N*HC

static __device__ __forceinline__ float bf2f(unsigned short u) {
    union { unsigned int i; float f; } x; x.i = ((unsigned int)u) << 16; return x.f;
}
static __device__ __forceinline__ unsigned short f2bf(float f) {
    union { float f; unsigned int i; } x; x.f = f;
    unsigned int r = x.i + 0x7FFFu + ((x.i >> 16) & 1u);   // RNE
    return (unsigned short)(r >> 16);
}

// ---------------- k0: decode single_mask (uint8 / int32 / float32) -> mterm[384] ----------------
__global__ __launch_bounds__(384) void k0_mask(const unsigned int* __restrict__ mu,
                                               float* __restrict__ mterm)
{
    __shared__ int byteLayout;
    if (threadIdx.x == 0) byteLayout = 0;
    __syncthreads();
    if (threadIdx.x < 96) {
        unsigned int u = mu[threadIdx.x];
        if (u != 0u && u != 1u && u != 0x3F800000u) atomicOr(&byteLayout, 1);
    }
    __syncthreads();
    const int j = threadIdx.x;
    int val;
    if (byteLayout) val = ((const unsigned char*)mu)[j];
    else            val = (mu[j] != 0u);
    mterm[j] = val ? 0.0f : -1e9f;
}

// ---------------- k1: LN(m) -> v = m_ln@w_v, g = sigmoid(m_ln@w_g)  (bf16 out) ----------------
__global__ __launch_bounds__(256) void k1_lnm_vg(
    const float* __restrict__ m, const float* __restrict__ lnw, const float* __restrict__ lnb,
    const float* __restrict__ w_v, const float* __restrict__ w_g,
    unsigned short* __restrict__ vout, unsigned short* __restrict__ gout)
{
    __shared__ float mln[16][64];
    const int tid = threadIdx.x, wave = tid >> 6, lane = tid & 63;
    const int rowBase = blockIdx.x * 16;
    const float lw = lnw[lane], lb = lnb[lane];
    for (int rr = wave; rr < 16; rr += 4) {
        float x = m[(size_t)(rowBase + rr) * CM + lane];
        float s1 = x, s2 = x * x;
        #pragma unroll
        for (int off = 32; off; off >>= 1) {
            s1 += __shfl_xor(s1, off);
            s2 += __shfl_xor(s2, off);
        }
        float mu  = s1 * (1.0f / CM);
        float var = s2 * (1.0f / CM) - mu * mu;
        mln[rr][lane] = (x - mu) * rsqrtf(var + 1e-5f) * lw + lb;
    }
    __syncthreads();

    float accv[16], accg[16];
    #pragma unroll
    for (int r = 0; r < 16; r++) { accv[r] = 0.f; accg[r] = 0.f; }

    for (int k = 0; k < CM; k += 4) {
        float wv[4], wg[4];
        #pragma unroll
        for (int q = 0; q < 4; q++) {
            wv[q] = w_v[(k + q) * HC + tid];
            wg[q] = w_g[(k + q) * HC + tid];
        }
        #pragma unroll
        for (int r = 0; r < 16; r++) {
            float4 mv = *(const float4*)&mln[r][k];
            accv[r] += mv.x * wv[0] + mv.y * wv[1] + mv.z * wv[2] + mv.w * wv[3];
            accg[r] += mv.x * wg[0] + mv.y * wg[1] + mv.z * wg[2] + mv.w * wg[3];
        }
    }
    #pragma unroll
    for (int r = 0; r < 16; r++) {
        size_t row = (size_t)(rowBase + r);
        vout[row * HC + tid] = f2bf(accv[r]);
        gout[row * HC + tid] = f2bf(1.0f / (1.0f + expf(-accg[r])));
    }
}

// ---------------- k2: LN(z) @ w_b + mask -> logits bl[h][i][j] (fp32) ----------------
__global__ __launch_bounds__(256) void k2_lnz_b(
    const float* __restrict__ z, const float* __restrict__ lnw, const float* __restrict__ lnb,
    const float* __restrict__ w_b, const float* __restrict__ mterm, float* __restrict__ bl)
{
    const int tid = threadIdx.x, wave = tid >> 6, lane = tid & 63;
    const int row = blockIdx.x * 4 + wave;          // = i*384 + j
    const int i = row / NN, j = row - i * NN;
    const float* zp = z + (size_t)row * CZ;
    float x0 = zp[lane], x1 = zp[64 + lane];
    float s1 = x0 + x1, s2 = x0 * x0 + x1 * x1;
    #pragma unroll
    for (int off = 32; off; off >>= 1) {
        s1 += __shfl_xor(s1, off);
        s2 += __shfl_xor(s2, off);
    }
    float mu  = s1 * (1.0f / CZ);
    float var = s2 * (1.0f / CZ) - mu * mu;
    float rstd = rsqrtf(var + 1e-5f);
    float y0 = (x0 - mu) * rstd * lnw[lane]      + lnb[lane];
    float y1 = (x1 - mu) * rstd * lnw[64 + lane] + lnb[64 + lane];
    float4 wa0 = *(const float4*)&w_b[lane * 8];
    float4 wa1 = *(const float4*)&w_b[lane * 8 + 4];
    float4 wb0 = *(const float4*)&w_b[(64 + lane) * 8];
    float4 wb1 = *(const float4*)&w_b[(64 + lane) * 8 + 4];
    float p[8];
    p[0] = y0 * wa0.x + y1 * wb0.x;
    p[1] = y0 * wa0.y + y1 * wb0.y;
    p[2] = y0 * wa0.z + y1 * wb0.z;
    p[3] = y0 * wa0.w + y1 * wb0.w;
    p[4] = y0 * wa1.x + y1 * wb1.x;
    p[5] = y0 * wa1.y + y1 * wb1.y;
    p[6] = y0 * wa1.z + y1 * wb1.z;
    p[7] = y0 * wa1.w + y1 * wb1.w;
    #pragma unroll
    for (int off = 32; off; off >>= 1) {
        #pragma unroll
        for (int h = 0; h < 8; h++) p[h] += __shfl_xor(p[h], off);
    }
    if (lane == 0) {
        float mt = mterm[j];
        #pragma unroll
        for (int h = 0; h < 8; h++)
            bl[((size_t)h * NN + i) * NN + j] = p[h] + mt;
    }
}

// ---------------- k3: softmax over j, in place on bl[h][i][:] ----------------
__global__ __launch_bounds__(256) void k3_softmax(float* __restrict__ bl)
{
    const int tid = threadIdx.x, wave = tid >> 6, lane = tid & 63;
    const int row = blockIdx.x * 4 + wave;   // = h*384 + i
    float* p = bl + (size_t)row * NN;
    float x[6];
    float mx = -1e30f;
    #pragma unroll
    for (int e = 0; e < 6; e++) { x[e] = p[lane + e * 64]; mx = fmaxf(mx, x[e]); }
    #pragma unroll
    for (int off = 32; off; off >>= 1) mx = fmaxf(mx, __shfl_xor(mx, off));
    float sum = 0.f;
    #pragma unroll
    for (int e = 0; e < 6; e++) { x[e] = expf(x[e] - mx); sum += x[e]; }
    #pragma unroll
    for (int off = 32; off; off >>= 1) sum += __shfl_xor(sum, off);
    float inv = 1.0f / sum;
    #pragma unroll
    for (int e = 0; e < 6; e++) p[lane + e * 64] = x[e] * inv;
}

// ---------------- k4: o[s,i,h,c] = sum_j w[h,i,j] * v[s,j,h,c]; fuse *g; go bf16 ----------------
__global__ __launch_bounds__(256) void k4_einsum(
    const float* __restrict__ wsm, const unsigned short* __restrict__ vbf,
    const unsigned short* __restrict__ gbf, unsigned short* __restrict__ gobf)
{
    __shared__ float Wl[64][36];
    __shared__ float Vl[32][64];
    const int tid = threadIdx.x;
    const int h  = blockIdx.z;
    const int i0 = blockIdx.y * 64;
    const int n0 = blockIdx.x * 64;  // sc tile base (2 s x 32 c)
    const int s0 = n0 >> 5;
    const int tx = tid & 15, ty = tid >> 4;

    float acc[4][4] = {};
    for (int k0 = 0; k0 < NN; k0 += 32) {
        #pragma unroll
        for (int e = 0; e < 8; e++) {
            int idx = tid + e * 256;
            int r = idx >> 5, c = idx & 31;
            Wl[r][c] = wsm[((size_t)h * NN + i0 + r) * NN + k0 + c];
        }
        #pragma unroll
        for (int e = 0; e < 8; e++) {
            int idx = tid + e * 256;
            int r = idx >> 6, c = idx & 63;
            int s = s0 + (c >> 5), cc = c & 31;
            Vl[r][c] = bf2f(vbf[((size_t)s * NN + (k0 + r)) * HC + h * CCc + cc]);
        }
        __syncthreads();
        #pragma unroll
        for (int kk = 0; kk < 32; kk += 4) {
            float a[4][4];
            #pragma unroll
            for (int mm = 0; mm < 4; mm++)
                *(float4*)a[mm] = *(const float4*)&Wl[ty * 4 + mm][kk];
            #pragma unroll
            for (int q = 0; q < 4; q++) {
                float4 b4 = *(const float4*)&Vl[kk + q][tx * 4];
                #pragma unroll
                for (int mm = 0; mm < 4; mm++) {
                    acc[mm][0] += a[mm][q] * b4.x;
                    acc[mm][1] += a[mm][q] * b4.y;
                    acc[mm][2] += a[mm][q] * b4.z;
                    acc[mm][3] += a[mm][q] * b4.w;
                }
            }
        }
        __syncthreads();
    }
    const int sc = n0 + tx * 4;
    const int s = sc >> 5, cc = sc & 31;
    #pragma unroll
    for (int mm = 0; mm < 4; mm++) {
        int i = i0 + ty * 4 + mm;
        size_t off = ((size_t)s * NN + i) * HC + h * CCc + cc;
        ushort4 gv = *(const ushort4*)&gbf[off];
        ushort4 o4;
        o4.x = f2bf(acc[mm][0] * bf2f(gv.x));
        o4.y = f2bf(acc[mm][1] * bf2f(gv.y));
        o4.z = f2bf(acc[mm][2] * bf2f(gv.z));
        o4.w = f2bf(acc[mm][3] * bf2f(gv.w));
        *(ushort4*)&gobf[off] = o4;
    }
}

// ---------------- k5: out = go @ w_out   [98304,256]@[256,64] ----------------
__global__ __launch_bounds__(256) void k5_out(
    const unsigned short* __restrict__ gobf, const float* __restrict__ w_out,
    float* __restrict__ out)
{
    __shared__ float wl[256 * 64];
    const int tid = threadIdx.x;
    #pragma unroll
    for (int e = 0; e < 16; e++) {
        int idx = (tid + e * 256) * 4;
        *(float4*)&wl[idx] = *(const float4*)&w_out[idx];
    }
    __syncthreads();
    const int col = tid & 63, rg = tid >> 6;
    const size_t rowBase = (size_t)blockIdx.x * 16;
    float acc[4] = {0.f, 0.f, 0.f, 0.f};
    for (int k = 0; k < HC; k += 4) {
        float w0 = wl[(k + 0) * 64 + col];
        float w1 = wl[(k + 1) * 64 + col];
        float w2 = wl[(k + 2) * 64 + col];
        float w3 = wl[(k + 3) * 64 + col];
        #pragma unroll
        for (int r = 0; r < 4; r++) {
            size_t row = rowBase + rg + r * 4;
            ushort4 gv = *(const ushort4*)&gobf[row * HC + k];
            acc[r] += bf2f(gv.x) * w0 + bf2f(gv.y) * w1 + bf2f(gv.z) * w2 + bf2f(gv.w) * w3;
        }
    }
    #pragma unroll
    for (int r = 0; r < 4; r++) {
        size_t row = rowBase + rg + r * 4;
        out[row * CM + col] = acc[r];
    }
}

extern "C" void kernel_launch(void* const* d_in, const int* in_sizes, int n_in,
                              void* d_out, int out_size, void* d_ws, size_t ws_size,
                              hipStream_t stream)
{
    const float* m      = (const float*)d_in[0];
    const float* z      = (const float*)d_in[1];
    const unsigned int* mask_raw = (const unsigned int*)d_in[2];
    const float* ln_m_w = (const float*)d_in[3];
    const float* ln_m_b = (const float*)d_in[4];
    const float* ln_z_w = (const float*)d_in[5];
    const float* ln_z_b = (const float*)d_in[6];
    const float* w_v    = (const float*)d_in[7];
    const float* w_b    = (const float*)d_in[8];
    const float* w_g    = (const float*)d_in[9];
    const float* w_out  = (const float*)d_in[10];
    float* out = (float*)d_out;

    // ws layout (bytes): bl fp32 4,718,592 | mterm 1,536 | v bf16 50,331,648 | g bf16 | go bf16
    float* bl    = (float*)d_ws;                       // [H,N,N] 1,179,648 f
    float* mterm = bl + 1179648;                       // [384] f
    unsigned short* v  = (unsigned short*)(mterm + 384);  // [S,N,HC] bf16
    unsigned short* g  = v + NV;
    unsigned short* go = g + NV;

    k0_mask<<<1, 384, 0, stream>>>(mask_raw, mterm);
    k1_lnm_vg<<<6144, 256, 0, stream>>>(m, ln_m_w, ln_m_b, w_v, w_g, v, g);
    k2_lnz_b<<<36864, 256, 0, stream>>>(z, ln_z_w, ln_z_b, w_b, mterm, bl);
    k3_softmax<<<768, 256, 0, stream>>>(bl);
    k4_einsum<<<dim3(128, 6, 8), 256, 0, stream>>>(bl, v, g, go);
    k5_out<<<6144, 256, 0, stream>>>(go, w_out, out);
}

// Round 4
// 461.507 us; speedup vs baseline: 1.3766x; 1.3766x over previous
//
#include <hip/hip_runtime.h>
#include <math.h>

// MSAPairWeightedAveraging — round 3: k4 einsum as bf16 MFMA GEMM (m97-style).
// S=256, N=384, C_M=64, C_Z=128, C=32, H=8, H*C=256.
// ws: mterm f32[384] | wbl bf16[8,384,384] | vT bf16[8,8192,384] | g bf16[98304,256] | ob bf16[98304,256]
//   = 153.4 MB

#define SS 256
#define NN 384
#define CM 64
#define CZ 128
#define HH 8
#define HC 256
#define NV 25165824   // S*N*HC

typedef __attribute__((ext_vector_type(8))) short short8v;
typedef __attribute__((ext_vector_type(8))) unsigned short ushort8v;
typedef __attribute__((ext_vector_type(4))) float f32x4;

static __device__ __forceinline__ float bf2f(unsigned short u) {
    union { unsigned int i; float f; } x; x.i = ((unsigned int)u) << 16; return x.f;
}
static __device__ __forceinline__ unsigned short f2bf(float f) {
    union { float f; unsigned int i; } x; x.f = f;
    unsigned int r = x.i + 0x7FFFu + ((x.i >> 16) & 1u);   // RNE
    return (unsigned short)(r >> 16);
}
static __device__ __forceinline__ void gload_lds16(const void* g, void* l) {
    __builtin_amdgcn_global_load_lds((const __attribute__((address_space(1))) void*)g,
                                     (__attribute__((address_space(3))) void*)l, 16, 0, 0);
}

// ---------------- k0: decode single_mask (uint8 / int32 / float32) -> mterm[384] ----------------
__global__ __launch_bounds__(384) void k0_mask(const unsigned int* __restrict__ mu,
                                               float* __restrict__ mterm)
{
    __shared__ int byteLayout;
    if (threadIdx.x == 0) byteLayout = 0;
    __syncthreads();
    if (threadIdx.x < 96) {
        unsigned int u = mu[threadIdx.x];
        if (u != 0u && u != 1u && u != 0x3F800000u) atomicOr(&byteLayout, 1);
    }
    __syncthreads();
    const int j = threadIdx.x;
    int val;
    if (byteLayout) val = ((const unsigned char*)mu)[j];
    else            val = (mu[j] != 0u);
    mterm[j] = val ? 0.0f : -1e9f;
}

// ---------------- k1: LN(m) -> vT[h][(s,c)][j] bf16, g[(s,n)][hc] bf16 ----------------
__global__ __launch_bounds__(256) void k1_lnm_vg(
    const float* __restrict__ m, const float* __restrict__ lnw, const float* __restrict__ lnb,
    const float* __restrict__ w_v, const float* __restrict__ w_g,
    unsigned short* __restrict__ vT, unsigned short* __restrict__ gout)
{
    __shared__ float mln[16][64];
    const int tid = threadIdx.x, wave = tid >> 6, lane = tid & 63;
    const int rowBase = blockIdx.x * 16;        // = s*384 + j0, j0 16-aligned (384%16==0)
    const int s  = rowBase / NN;
    const int j0 = rowBase - s * NN;
    const float lw = lnw[lane], lb = lnb[lane];
    for (int rr = wave; rr < 16; rr += 4) {
        float x = m[(size_t)(rowBase + rr) * CM + lane];
        float s1 = x, s2 = x * x;
        #pragma unroll
        for (int off = 32; off; off >>= 1) {
            s1 += __shfl_xor(s1, off);
            s2 += __shfl_xor(s2, off);
        }
        float mu  = s1 * (1.0f / CM);
        float var = s2 * (1.0f / CM) - mu * mu;
        mln[rr][lane] = (x - mu) * rsqrtf(var + 1e-5f) * lw + lb;
    }
    __syncthreads();

    float accv[16], accg[16];
    #pragma unroll
    for (int r = 0; r < 16; r++) { accv[r] = 0.f; accg[r] = 0.f; }

    for (int k = 0; k < CM; k += 4) {
        float wv[4], wg[4];
        #pragma unroll
        for (int q = 0; q < 4; q++) {
            wv[q] = w_v[(k + q) * HC + tid];
            wg[q] = w_g[(k + q) * HC + tid];
        }
        #pragma unroll
        for (int r = 0; r < 16; r++) {
            float4 mv = *(const float4*)&mln[r][k];
            accv[r] += mv.x * wv[0] + mv.y * wv[1] + mv.z * wv[2] + mv.w * wv[3];
            accg[r] += mv.x * wg[0] + mv.y * wg[1] + mv.z * wg[2] + mv.w * wg[3];
        }
    }
    // g: normal layout
    #pragma unroll
    for (int r = 0; r < 16; r++)
        gout[(size_t)(rowBase + r) * HC + tid] = f2bf(1.0f / (1.0f + expf(-accg[r])));
    // vT: thread owns (h = tid>>5, c = tid&31); 16 consecutive j values -> two 16B stores
    const int hh = tid >> 5, cc = tid & 31;
    ushort8v p0, p1;
    #pragma unroll
    for (int r = 0; r < 8; r++) { p0[r] = f2bf(accv[r]); p1[r] = f2bf(accv[8 + r]); }
    size_t vtoff = ((size_t)(hh * 8192 + s * 32 + cc)) * NN + j0;
    *(ushort8v*)&vT[vtoff]     = p0;
    *(ushort8v*)&vT[vtoff + 8] = p1;
}

// ---------------- k2: LN(z) @ w_b + mask -> logits bf16 wbl[h][i][j] ----------------
__global__ __launch_bounds__(256) void k2_lnz_b(
    const float* __restrict__ z, const float* __restrict__ lnw, const float* __restrict__ lnb,
    const float* __restrict__ w_b, const float* __restrict__ mterm, unsigned short* __restrict__ wbl)
{
    const int tid = threadIdx.x, wave = tid >> 6, lane = tid & 63;
    const int row = blockIdx.x * 4 + wave;          // = i*384 + j
    const int i = row / NN, j = row - i * NN;
    const float* zp = z + (size_t)row * CZ;
    float x0 = zp[lane], x1 = zp[64 + lane];
    float s1 = x0 + x1, s2 = x0 * x0 + x1 * x1;
    #pragma unroll
    for (int off = 32; off; off >>= 1) {
        s1 += __shfl_xor(s1, off);
        s2 += __shfl_xor(s2, off);
    }
    float mu  = s1 * (1.0f / CZ);
    float var = s2 * (1.0f / CZ) - mu * mu;
    float rstd = rsqrtf(var + 1e-5f);
    float y0 = (x0 - mu) * rstd * lnw[lane]      + lnb[lane];
    float y1 = (x1 - mu) * rstd * lnw[64 + lane] + lnb[64 + lane];
    float4 wa0 = *(const float4*)&w_b[lane * 8];
    float4 wa1 = *(const float4*)&w_b[lane * 8 + 4];
    float4 wb0 = *(const float4*)&w_b[(64 + lane) * 8];
    float4 wb1 = *(const float4*)&w_b[(64 + lane) * 8 + 4];
    float p[8];
    p[0] = y0 * wa0.x + y1 * wb0.x;
    p[1] = y0 * wa0.y + y1 * wb0.y;
    p[2] = y0 * wa0.z + y1 * wb0.z;
    p[3] = y0 * wa0.w + y1 * wb0.w;
    p[4] = y0 * wa1.x + y1 * wb1.x;
    p[5] = y0 * wa1.y + y1 * wb1.y;
    p[6] = y0 * wa1.z + y1 * wb1.z;
    p[7] = y0 * wa1.w + y1 * wb1.w;
    #pragma unroll
    for (int off = 32; off; off >>= 1) {
        #pragma unroll
        for (int h = 0; h < 8; h++) p[h] += __shfl_xor(p[h], off);
    }
    if (lane == 0) {
        float mt = mterm[j];
        #pragma unroll
        for (int h = 0; h < 8; h++)
            wbl[((size_t)h * NN + i) * NN + j] = f2bf(p[h] + mt);
    }
}

// ---------------- k3: softmax over j, bf16 in place on wbl[h][i][:] ----------------
__global__ __launch_bounds__(256) void k3_softmax(unsigned short* __restrict__ wbl)
{
    const int tid = threadIdx.x, wave = tid >> 6, lane = tid & 63;
    const int row = blockIdx.x * 4 + wave;   // = h*384 + i
    unsigned short* p = wbl + (size_t)row * NN;
    float x[6];
    float mx = -1e30f;
    #pragma unroll
    for (int e = 0; e < 6; e++) { x[e] = bf2f(p[lane + e * 64]); mx = fmaxf(mx, x[e]); }
    #pragma unroll
    for (int off = 32; off; off >>= 1) mx = fmaxf(mx, __shfl_xor(mx, off));
    float sum = 0.f;
    #pragma unroll
    for (int e = 0; e < 6; e++) { x[e] = expf(x[e] - mx); sum += x[e]; }
    #pragma unroll
    for (int off = 32; off; off >>= 1) sum += __shfl_xor(sum, off);
    float inv = 1.0f / sum;
    #pragma unroll
    for (int e = 0; e < 6; e++) p[lane + e * 64] = f2bf(x[e] * inv);
}

// ---------------- k4: per-h MFMA GEMM  o[i][sc] = W[h] (384x384) x vT[h]^T (384x8192) ----------------
// 128x128 tile, BK=32, 4 waves (2x2), each wave 64x64 = 4x4 fragments of 16x16x32 bf16.
__global__ __launch_bounds__(256) void k4_mfma(
    const unsigned short* __restrict__ wbf, const unsigned short* __restrict__ vT,
    unsigned short* __restrict__ ob)
{
    __shared__ unsigned short Al[128 * 32];   // A tile  [i-rows][k]
    __shared__ unsigned short Bl[128 * 32];   // B^T tile [n-rows][k]
    const int tid  = threadIdx.x;
    const int wid  = tid >> 6, lane = tid & 63;
    const int wm   = wid >> 1, wn = wid & 1;
    const int h    = blockIdx.z;
    const int i0   = blockIdx.y * 128;
    const int n0   = blockIdx.x * 128;
    const unsigned short* Ag = wbf + (size_t)h * NN * NN;       // [384][384]
    const unsigned short* Bg = vT  + (size_t)h * 8192 * NN;     // [8192][384]

    f32x4 acc[4][4] = {};

    const int lrow = lane >> 2, lchunk = lane & 3;   // staging: 16 rows x 4 chunks of 16B per issue
    for (int k0 = 0; k0 < NN; k0 += 32) {
        #pragma unroll
        for (int q = 0; q < 2; q++) {
            int issue = wid * 2 + q;                  // 0..7 -> rows [issue*16, +16)
            int r = issue * 16 + lrow;
            gload_lds16(Ag + (size_t)(i0 + r) * NN + k0 + lchunk * 8,
                        (void*)((char*)Al + issue * 1024));
            gload_lds16(Bg + (size_t)(n0 + r) * NN + k0 + lchunk * 8,
                        (void*)((char*)Bl + issue * 1024));
        }
        __syncthreads();   // drains vmcnt + barrier

        short8v a[4], b[4];
        #pragma unroll
        for (int mi = 0; mi < 4; mi++)
            a[mi] = *(const short8v*)&Al[(wm * 64 + mi * 16 + (lane & 15)) * 32 + (lane >> 4) * 8];
        #pragma unroll
        for (int ni = 0; ni < 4; ni++)
            b[ni] = *(const short8v*)&Bl[(wn * 64 + ni * 16 + (lane & 15)) * 32 + (lane >> 4) * 8];
        #pragma unroll
        for (int mi = 0; mi < 4; mi++)
            #pragma unroll
            for (int ni = 0; ni < 4; ni++)
                acc[mi][ni] = __builtin_amdgcn_mfma_f32_16x16x32_bf16(a[mi], b[ni], acc[mi][ni], 0, 0, 0);
        __syncthreads();
    }

    // C/D layout: col = lane&15, row = (lane>>4)*4 + reg   -> i = row-dim, n = col-dim
    #pragma unroll
    for (int mi = 0; mi < 4; mi++) {
        const int ibase = i0 + wm * 64 + mi * 16 + ((lane >> 4) << 2);
        #pragma unroll
        for (int ni = 0; ni < 4; ni++) {
            const int n = n0 + wn * 64 + ni * 16 + (lane & 15);
            const int s = n >> 5, c = n & 31;
            #pragma unroll
            for (int r = 0; r < 4; r++)
                ob[((size_t)s * NN + (ibase + r)) * HC + (h << 5) + c] = f2bf(acc[mi][ni][r]);
        }
    }
}

// ---------------- k5: out = (g .* o) @ w_out   [98304,256]@[256,64], fp32 out ----------------
__global__ __launch_bounds__(256) void k5_out(
    const unsigned short* __restrict__ ob, const unsigned short* __restrict__ g,
    const float* __restrict__ w_out, float* __restrict__ out)
{
    __shared__ unsigned short wl[256 * 64];   // bf16 w_out, 32 KB
    const int tid = threadIdx.x;
    #pragma unroll
    for (int e = 0; e < 16; e++) {
        int idx = (tid + e * 256) * 4;
        float4 w4 = *(const float4*)&w_out[idx];
        wl[idx + 0] = f2bf(w4.x); wl[idx + 1] = f2bf(w4.y);
        wl[idx + 2] = f2bf(w4.z); wl[idx + 3] = f2bf(w4.w);
    }
    __syncthreads();
    const int col = tid & 63, rg = tid >> 6;
    const size_t rowBase = (size_t)blockIdx.x * 16;
    float acc[4] = {0.f, 0.f, 0.f, 0.f};
    for (int k = 0; k < HC; k += 8) {
        float wv[8];
        #pragma unroll
        for (int q = 0; q < 8; q++) wv[q] = bf2f(wl[(k + q) * 64 + col]);
        #pragma unroll
        for (int r = 0; r < 4; r++) {
            size_t row = rowBase + rg + r * 4;
            ushort8v o8 = *(const ushort8v*)&ob[row * HC + k];
            ushort8v g8 = *(const ushort8v*)&g[row * HC + k];
            #pragma unroll
            for (int q = 0; q < 8; q++)
                acc[r] += bf2f(o8[q]) * bf2f(g8[q]) * wv[q];
        }
    }
    #pragma unroll
    for (int r = 0; r < 4; r++) {
        size_t row = rowBase + rg + r * 4;
        out[row * CM + col] = acc[r];
    }
}

extern "C" void kernel_launch(void* const* d_in, const int* in_sizes, int n_in,
                              void* d_out, int out_size, void* d_ws, size_t ws_size,
                              hipStream_t stream)
{
    const float* m      = (const float*)d_in[0];
    const float* z      = (const float*)d_in[1];
    const unsigned int* mask_raw = (const unsigned int*)d_in[2];
    const float* ln_m_w = (const float*)d_in[3];
    const float* ln_m_b = (const float*)d_in[4];
    const float* ln_z_w = (const float*)d_in[5];
    const float* ln_z_b = (const float*)d_in[6];
    const float* w_v    = (const float*)d_in[7];
    const float* w_b    = (const float*)d_in[8];
    const float* w_g    = (const float*)d_in[9];
    const float* w_out  = (const float*)d_in[10];
    float* out = (float*)d_out;

    // ws: mterm f32[384] | wbl bf16[1179648] | vT bf16[NV] | g bf16[NV] | ob bf16[NV]
    float* mterm = (float*)d_ws;
    unsigned short* wbl = (unsigned short*)(mterm + 384);
    unsigned short* vT  = wbl + 1179648;
    unsigned short* g   = vT + NV;
    unsigned short* ob  = g + NV;

    k0_mask<<<1, 384, 0, stream>>>(mask_raw, mterm);
    k1_lnm_vg<<<6144, 256, 0, stream>>>(m, ln_m_w, ln_m_b, w_v, w_g, vT, g);
    k2_lnz_b<<<36864, 256, 0, stream>>>(z, ln_z_w, ln_z_b, w_b, mterm, wbl);
    k3_softmax<<<768, 256, 0, stream>>>(wbl);
    k4_mfma<<<dim3(64, 3, 8), 256, 0, stream>>>(wbl, vT, ob);
    k5_out<<<6144, 256, 0, stream>>>(ob, g, w_out, out);
}

// Round 5
// 461.493 us; speedup vs baseline: 1.3766x; 1.0000x over previous
//
#include <hip/hip_runtime.h>
#include <math.h>

// MSAPairWeightedAveraging — round 3: k4 einsum as bf16 MFMA GEMM (m97-style).
// S=256, N=384, C_M=64, C_Z=128, C=32, H=8, H*C=256.
// ws: mterm f32[384] | wbl bf16[8,384,384] | vT bf16[8,8192,384] | g bf16[98304,256] | ob bf16[98304,256]
//   = 153.4 MB

#define SS 256
#define NN 384
#define CM 64
#define CZ 128
#define HH 8
#define HC 256
#define NV 25165824   // S*N*HC

typedef __attribute__((ext_vector_type(8))) short short8v;
typedef __attribute__((ext_vector_type(8))) unsigned short ushort8v;
typedef __attribute__((ext_vector_type(4))) float f32x4;

static __device__ __forceinline__ float bf2f(unsigned short u) {
    union { unsigned int i; float f; } x; x.i = ((unsigned int)u) << 16; return x.f;
}
static __device__ __forceinline__ unsigned short f2bf(float f) {
    union { float f; unsigned int i; } x; x.f = f;
    unsigned int r = x.i + 0x7FFFu + ((x.i >> 16) & 1u);   // RNE
    return (unsigned short)(r >> 16);
}
static __device__ __forceinline__ void gload_lds16(const void* g, void* l) {
    __builtin_amdgcn_global_load_lds((const __attribute__((address_space(1))) void*)g,
                                     (__attribute__((address_space(3))) void*)l, 16, 0, 0);
}

// ---------------- k0: decode single_mask (uint8 / int32 / float32) -> mterm[384] ----------------
__global__ __launch_bounds__(384) void k0_mask(const unsigned int* __restrict__ mu,
                                               float* __restrict__ mterm)
{
    __shared__ int byteLayout;
    if (threadIdx.x == 0) byteLayout = 0;
    __syncthreads();
    if (threadIdx.x < 96) {
        unsigned int u = mu[threadIdx.x];
        if (u != 0u && u != 1u && u != 0x3F800000u) atomicOr(&byteLayout, 1);
    }
    __syncthreads();
    const int j = threadIdx.x;
    int val;
    if (byteLayout) val = ((const unsigned char*)mu)[j];
    else            val = (mu[j] != 0u);
    mterm[j] = val ? 0.0f : -1e9f;
}

// ---------------- k1: LN(m) -> vT[h][(s,c)][j] bf16, g[(s,n)][hc] bf16 ----------------
__global__ __launch_bounds__(256) void k1_lnm_vg(
    const float* __restrict__ m, const float* __restrict__ lnw, const float* __restrict__ lnb,
    const float* __restrict__ w_v, const float* __restrict__ w_g,
    unsigned short* __restrict__ vT, unsigned short* __restrict__ gout)
{
    __shared__ float mln[16][64];
    const int tid = threadIdx.x, wave = tid >> 6, lane = tid & 63;
    const int rowBase = blockIdx.x * 16;        // = s*384 + j0, j0 16-aligned (384%16==0)
    const int s  = rowBase / NN;
    const int j0 = rowBase - s * NN;
    const float lw = lnw[lane], lb = lnb[lane];
    for (int rr = wave; rr < 16; rr += 4) {
        float x = m[(size_t)(rowBase + rr) * CM + lane];
        float s1 = x, s2 = x * x;
        #pragma unroll
        for (int off = 32; off; off >>= 1) {
            s1 += __shfl_xor(s1, off);
            s2 += __shfl_xor(s2, off);
        }
        float mu  = s1 * (1.0f / CM);
        float var = s2 * (1.0f / CM) - mu * mu;
        mln[rr][lane] = (x - mu) * rsqrtf(var + 1e-5f) * lw + lb;
    }
    __syncthreads();

    float accv[16], accg[16];
    #pragma unroll
    for (int r = 0; r < 16; r++) { accv[r] = 0.f; accg[r] = 0.f; }

    for (int k = 0; k < CM; k += 4) {
        float wv[4], wg[4];
        #pragma unroll
        for (int q = 0; q < 4; q++) {
            wv[q] = w_v[(k + q) * HC + tid];
            wg[q] = w_g[(k + q) * HC + tid];
        }
        #pragma unroll
        for (int r = 0; r < 16; r++) {
            float4 mv = *(const float4*)&mln[r][k];
            accv[r] += mv.x * wv[0] + mv.y * wv[1] + mv.z * wv[2] + mv.w * wv[3];
            accg[r] += mv.x * wg[0] + mv.y * wg[1] + mv.z * wg[2] + mv.w * wg[3];
        }
    }
    // g: normal layout
    #pragma unroll
    for (int r = 0; r < 16; r++)
        gout[(size_t)(rowBase + r) * HC + tid] = f2bf(1.0f / (1.0f + expf(-accg[r])));
    // vT: thread owns (h = tid>>5, c = tid&31); 16 consecutive j values -> two 16B stores
    const int hh = tid >> 5, cc = tid & 31;
    ushort8v p0, p1;
    #pragma unroll
    for (int r = 0; r < 8; r++) { p0[r] = f2bf(accv[r]); p1[r] = f2bf(accv[8 + r]); }
    size_t vtoff = ((size_t)(hh * 8192 + s * 32 + cc)) * NN + j0;
    *(ushort8v*)&vT[vtoff]     = p0;
    *(ushort8v*)&vT[vtoff + 8] = p1;
}

// ---------------- k2: LN(z) @ w_b + mask -> logits bf16 wbl[h][i][j] ----------------
__global__ __launch_bounds__(256) void k2_lnz_b(
    const float* __restrict__ z, const float* __restrict__ lnw, const float* __restrict__ lnb,
    const float* __restrict__ w_b, const float* __restrict__ mterm, unsigned short* __restrict__ wbl)
{
    const int tid = threadIdx.x, wave = tid >> 6, lane = tid & 63;
    const int row = blockIdx.x * 4 + wave;          // = i*384 + j
    const int i = row / NN, j = row - i * NN;
    const float* zp = z + (size_t)row * CZ;
    float x0 = zp[lane], x1 = zp[64 + lane];
    float s1 = x0 + x1, s2 = x0 * x0 + x1 * x1;
    #pragma unroll
    for (int off = 32; off; off >>= 1) {
        s1 += __shfl_xor(s1, off);
        s2 += __shfl_xor(s2, off);
    }
    float mu  = s1 * (1.0f / CZ);
    float var = s2 * (1.0f / CZ) - mu * mu;
    float rstd = rsqrtf(var + 1e-5f);
    float y0 = (x0 - mu) * rstd * lnw[lane]      + lnb[lane];
    float y1 = (x1 - mu) * rstd * lnw[64 + lane] + lnb[64 + lane];
    float4 wa0 = *(const float4*)&w_b[lane * 8];
    float4 wa1 = *(const float4*)&w_b[lane * 8 + 4];
    float4 wb0 = *(const float4*)&w_b[(64 + lane) * 8];
    float4 wb1 = *(const float4*)&w_b[(64 + lane) * 8 + 4];
    float p[8];
    p[0] = y0 * wa0.x + y1 * wb0.x;
    p[1] = y0 * wa0.y + y1 * wb0.y;
    p[2] = y0 * wa0.z + y1 * wb0.z;
    p[3] = y0 * wa0.w + y1 * wb0.w;
    p[4] = y0 * wa1.x + y1 * wb1.x;
    p[5] = y0 * wa1.y + y1 * wb1.y;
    p[6] = y0 * wa1.z + y1 * wb1.z;
    p[7] = y0 * wa1.w + y1 * wb1.w;
    #pragma unroll
    for (int off = 32; off; off >>= 1) {
        #pragma unroll
        for (int h = 0; h < 8; h++) p[h] += __shfl_xor(p[h], off);
    }
    if (lane == 0) {
        float mt = mterm[j];
        #pragma unroll
        for (int h = 0; h < 8; h++)
            wbl[((size_t)h * NN + i) * NN + j] = f2bf(p[h] + mt);
    }
}

// ---------------- k3: softmax over j, bf16 in place on wbl[h][i][:] ----------------
__global__ __launch_bounds__(256) void k3_softmax(unsigned short* __restrict__ wbl)
{
    const int tid = threadIdx.x, wave = tid >> 6, lane = tid & 63;
    const int row = blockIdx.x * 4 + wave;   // = h*384 + i
    unsigned short* p = wbl + (size_t)row * NN;
    float x[6];
    float mx = -1e30f;
    #pragma unroll
    for (int e = 0; e < 6; e++) { x[e] = bf2f(p[lane + e * 64]); mx = fmaxf(mx, x[e]); }
    #pragma unroll
    for (int off = 32; off; off >>= 1) mx = fmaxf(mx, __shfl_xor(mx, off));
    float sum = 0.f;
    #pragma unroll
    for (int e = 0; e < 6; e++) { x[e] = expf(x[e] - mx); sum += x[e]; }
    #pragma unroll
    for (int off = 32; off; off >>= 1) sum += __shfl_xor(sum, off);
    float inv = 1.0f / sum;
    #pragma unroll
    for (int e = 0; e < 6; e++) p[lane + e * 64] = f2bf(x[e] * inv);
}

// ---------------- k4: per-h MFMA GEMM  o[i][sc] = W[h] (384x384) x vT[h]^T (384x8192) ----------------
// 128x128 tile, BK=32, 4 waves (2x2), each wave 64x64 = 4x4 fragments of 16x16x32 bf16.
__global__ __launch_bounds__(256) void k4_mfma(
    const unsigned short* __restrict__ wbf, const unsigned short* __restrict__ vT,
    unsigned short* __restrict__ ob)
{
    __shared__ unsigned short Al[128 * 32];   // A tile  [i-rows][k]
    __shared__ unsigned short Bl[128 * 32];   // B^T tile [n-rows][k]
    const int tid  = threadIdx.x;
    const int wid  = tid >> 6, lane = tid & 63;
    const int wm   = wid >> 1, wn = wid & 1;
    const int h    = blockIdx.z;
    const int i0   = blockIdx.y * 128;
    const int n0   = blockIdx.x * 128;
    const unsigned short* Ag = wbf + (size_t)h * NN * NN;       // [384][384]
    const unsigned short* Bg = vT  + (size_t)h * 8192 * NN;     // [8192][384]

    f32x4 acc[4][4] = {};

    const int lrow = lane >> 2, lchunk = lane & 3;   // staging: 16 rows x 4 chunks of 16B per issue
    for (int k0 = 0; k0 < NN; k0 += 32) {
        #pragma unroll
        for (int q = 0; q < 2; q++) {
            int issue = wid * 2 + q;                  // 0..7 -> rows [issue*16, +16)
            int r = issue * 16 + lrow;
            gload_lds16(Ag + (size_t)(i0 + r) * NN + k0 + lchunk * 8,
                        (void*)((char*)Al + issue * 1024));
            gload_lds16(Bg + (size_t)(n0 + r) * NN + k0 + lchunk * 8,
                        (void*)((char*)Bl + issue * 1024));
        }
        __syncthreads();   // drains vmcnt + barrier

        short8v a[4], b[4];
        #pragma unroll
        for (int mi = 0; mi < 4; mi++)
            a[mi] = *(const short8v*)&Al[(wm * 64 + mi * 16 + (lane & 15)) * 32 + (lane >> 4) * 8];
        #pragma unroll
        for (int ni = 0; ni < 4; ni++)
            b[ni] = *(const short8v*)&Bl[(wn * 64 + ni * 16 + (lane & 15)) * 32 + (lane >> 4) * 8];
        #pragma unroll
        for (int mi = 0; mi < 4; mi++)
            #pragma unroll
            for (int ni = 0; ni < 4; ni++)
                acc[mi][ni] = __builtin_amdgcn_mfma_f32_16x16x32_bf16(a[mi], b[ni], acc[mi][ni], 0, 0, 0);
        __syncthreads();
    }

    // C/D layout: col = lane&15, row = (lane>>4)*4 + reg   -> i = row-dim, n = col-dim
    #pragma unroll
    for (int mi = 0; mi < 4; mi++) {
        const int ibase = i0 + wm * 64 + mi * 16 + ((lane >> 4) << 2);
        #pragma unroll
        for (int ni = 0; ni < 4; ni++) {
            const int n = n0 + wn * 64 + ni * 16 + (lane & 15);
            const int s = n >> 5, c = n & 31;
            #pragma unroll
            for (int r = 0; r < 4; r++)
                ob[((size_t)s * NN + (ibase + r)) * HC + (h << 5) + c] = f2bf(acc[mi][ni][r]);
        }
    }
}

// ---------------- k5: out = (g .* o) @ w_out   [98304,256]@[256,64], fp32 out ----------------
__global__ __launch_bounds__(256) void k5_out(
    const unsigned short* __restrict__ ob, const unsigned short* __restrict__ g,
    const float* __restrict__ w_out, float* __restrict__ out)
{
    __shared__ unsigned short wl[256 * 64];   // bf16 w_out, 32 KB
    const int tid = threadIdx.x;
    #pragma unroll
    for (int e = 0; e < 16; e++) {
        int idx = (tid + e * 256) * 4;
        float4 w4 = *(const float4*)&w_out[idx];
        wl[idx + 0] = f2bf(w4.x); wl[idx + 1] = f2bf(w4.y);
        wl[idx + 2] = f2bf(w4.z); wl[idx + 3] = f2bf(w4.w);
    }
    __syncthreads();
    const int col = tid & 63, rg = tid >> 6;
    const size_t rowBase = (size_t)blockIdx.x * 16;
    float acc[4] = {0.f, 0.f, 0.f, 0.f};
    for (int k = 0; k < HC; k += 8) {
        float wv[8];
        #pragma unroll
        for (int q = 0; q < 8; q++) wv[q] = bf2f(wl[(k + q) * 64 + col]);
        #pragma unroll
        for (int r = 0; r < 4; r++) {
            size_t row = rowBase + rg + r * 4;
            ushort8v o8 = *(const ushort8v*)&ob[row * HC + k];
            ushort8v g8 = *(const ushort8v*)&g[row * HC + k];
            #pragma unroll
            for (int q = 0; q < 8; q++)
                acc[r] += bf2f(o8[q]) * bf2f(g8[q]) * wv[q];
        }
    }
    #pragma unroll
    for (int r = 0; r < 4; r++) {
        size_t row = rowBase + rg + r * 4;
        out[row * CM + col] = acc[r];
    }
}

extern "C" void kernel_launch(void* const* d_in, const int* in_sizes, int n_in,
                              void* d_out, int out_size, void* d_ws, size_t ws_size,
                              hipStream_t stream)
{
    const float* m      = (const float*)d_in[0];
    const float* z      = (const float*)d_in[1];
    const unsigned int* mask_raw = (const unsigned int*)d_in[2];
    const float* ln_m_w = (const float*)d_in[3];
    const float* ln_m_b = (const float*)d_in[4];
    const float* ln_z_w = (const float*)d_in[5];
    const float* ln_z_b = (const float*)d_in[6];
    const float* w_v    = (const float*)d_in[7];
    const float* w_b    = (const float*)d_in[8];
    const float* w_g    = (const float*)d_in[9];
    const float* w_out  = (const float*)d_in[10];
    float* out = (float*)d_out;

    // ws: mterm f32[384] | wbl bf16[1179648] | vT bf16[NV] | g bf16[NV] | ob bf16[NV]
    float* mterm = (float*)d_ws;
    unsigned short* wbl = (unsigned short*)(mterm + 384);
    unsigned short* vT  = wbl + 1179648;
    unsigned short* g   = vT + NV;
    unsigned short* ob  = g + NV;

    k0_mask<<<1, 384, 0, stream>>>(mask_raw, mterm);
    k1_lnm_vg<<<6144, 256, 0, stream>>>(m, ln_m_w, ln_m_b, w_v, w_g, vT, g);
    k2_lnz_b<<<36864, 256, 0, stream>>>(z, ln_z_w, ln_z_b, w_b, mterm, wbl);
    k3_softmax<<<768, 256, 0, stream>>>(wbl);
    k4_mfma<<<dim3(64, 3, 8), 256, 0, stream>>>(wbl, vT, ob);
    k5_out<<<6144, 256, 0, stream>>>(ob, g, w_out, out);
}

// Round 6
// 299.629 us; speedup vs baseline: 2.1203x; 1.5402x over previous
//
#include <hip/hip_runtime.h>
#include <math.h>

// MSAPairWeightedAveraging — round 5: k5 -> bf16 MFMA GEMM (o.*g)@w_out.
// S=256, N=384, C_M=64, C_Z=128, C=32, H=8, H*C=256.
// ws: mterm f32[384] | wbl bf16[8,384,384] | vT bf16[8,8192,384] | g bf16[98304,256] | ob bf16[98304,256]

#define SS 256
#define NN 384
#define CM 64
#define CZ 128
#define HH 8
#define HC 256
#define NV 25165824   // S*N*HC

typedef __attribute__((ext_vector_type(8))) short short8v;
typedef __attribute__((ext_vector_type(8))) unsigned short ushort8v;
typedef __attribute__((ext_vector_type(4))) float f32x4;

static __device__ __forceinline__ float bf2f(unsigned short u) {
    union { unsigned int i; float f; } x; x.i = ((unsigned int)u) << 16; return x.f;
}
static __device__ __forceinline__ unsigned short f2bf(float f) {
    union { float f; unsigned int i; } x; x.f = f;
    unsigned int r = x.i + 0x7FFFu + ((x.i >> 16) & 1u);   // RNE
    return (unsigned short)(r >> 16);
}
static __device__ __forceinline__ void gload_lds16(const void* g, void* l) {
    __builtin_amdgcn_global_load_lds((const __attribute__((address_space(1))) void*)g,
                                     (__attribute__((address_space(3))) void*)l, 16, 0, 0);
}

// ---------------- k0: decode single_mask (uint8 / int32 / float32) -> mterm[384] ----------------
__global__ __launch_bounds__(384) void k0_mask(const unsigned int* __restrict__ mu,
                                               float* __restrict__ mterm)
{
    __shared__ int byteLayout;
    if (threadIdx.x == 0) byteLayout = 0;
    __syncthreads();
    if (threadIdx.x < 96) {
        unsigned int u = mu[threadIdx.x];
        if (u != 0u && u != 1u && u != 0x3F800000u) atomicOr(&byteLayout, 1);
    }
    __syncthreads();
    const int j = threadIdx.x;
    int val;
    if (byteLayout) val = ((const unsigned char*)mu)[j];
    else            val = (mu[j] != 0u);
    mterm[j] = val ? 0.0f : -1e9f;
}

// ---------------- k1: LN(m) -> vT[h][(s,c)][j] bf16, g[(s,n)][hc] bf16 ----------------
__global__ __launch_bounds__(256) void k1_lnm_vg(
    const float* __restrict__ m, const float* __restrict__ lnw, const float* __restrict__ lnb,
    const float* __restrict__ w_v, const float* __restrict__ w_g,
    unsigned short* __restrict__ vT, unsigned short* __restrict__ gout)
{
    __shared__ float mln[16][64];
    const int tid = threadIdx.x, wave = tid >> 6, lane = tid & 63;
    const int rowBase = blockIdx.x * 16;        // = s*384 + j0, j0 16-aligned (384%16==0)
    const int s  = rowBase / NN;
    const int j0 = rowBase - s * NN;
    const float lw = lnw[lane], lb = lnb[lane];
    for (int rr = wave; rr < 16; rr += 4) {
        float x = m[(size_t)(rowBase + rr) * CM + lane];
        float s1 = x, s2 = x * x;
        #pragma unroll
        for (int off = 32; off; off >>= 1) {
            s1 += __shfl_xor(s1, off);
            s2 += __shfl_xor(s2, off);
        }
        float mu  = s1 * (1.0f / CM);
        float var = s2 * (1.0f / CM) - mu * mu;
        mln[rr][lane] = (x - mu) * rsqrtf(var + 1e-5f) * lw + lb;
    }
    __syncthreads();

    float accv[16], accg[16];
    #pragma unroll
    for (int r = 0; r < 16; r++) { accv[r] = 0.f; accg[r] = 0.f; }

    for (int k = 0; k < CM; k += 4) {
        float wv[4], wg[4];
        #pragma unroll
        for (int q = 0; q < 4; q++) {
            wv[q] = w_v[(k + q) * HC + tid];
            wg[q] = w_g[(k + q) * HC + tid];
        }
        #pragma unroll
        for (int r = 0; r < 16; r++) {
            float4 mv = *(const float4*)&mln[r][k];
            accv[r] += mv.x * wv[0] + mv.y * wv[1] + mv.z * wv[2] + mv.w * wv[3];
            accg[r] += mv.x * wg[0] + mv.y * wg[1] + mv.z * wg[2] + mv.w * wg[3];
        }
    }
    // g: normal layout
    #pragma unroll
    for (int r = 0; r < 16; r++)
        gout[(size_t)(rowBase + r) * HC + tid] = f2bf(1.0f / (1.0f + expf(-accg[r])));
    // vT: thread owns (h = tid>>5, c = tid&31); 16 consecutive j values -> two 16B stores
    const int hh = tid >> 5, cc = tid & 31;
    ushort8v p0, p1;
    #pragma unroll
    for (int r = 0; r < 8; r++) { p0[r] = f2bf(accv[r]); p1[r] = f2bf(accv[8 + r]); }
    size_t vtoff = ((size_t)(hh * 8192 + s * 32 + cc)) * NN + j0;
    *(ushort8v*)&vT[vtoff]     = p0;
    *(ushort8v*)&vT[vtoff + 8] = p1;
}

// ---------------- k2: LN(z) @ w_b + mask -> logits bf16 wbl[h][i][j] ----------------
__global__ __launch_bounds__(256) void k2_lnz_b(
    const float* __restrict__ z, const float* __restrict__ lnw, const float* __restrict__ lnb,
    const float* __restrict__ w_b, const float* __restrict__ mterm, unsigned short* __restrict__ wbl)
{
    const int tid = threadIdx.x, wave = tid >> 6, lane = tid & 63;
    const int row = blockIdx.x * 4 + wave;          // = i*384 + j
    const int i = row / NN, j = row - i * NN;
    const float* zp = z + (size_t)row * CZ;
    float x0 = zp[lane], x1 = zp[64 + lane];
    float s1 = x0 + x1, s2 = x0 * x0 + x1 * x1;
    #pragma unroll
    for (int off = 32; off; off >>= 1) {
        s1 += __shfl_xor(s1, off);
        s2 += __shfl_xor(s2, off);
    }
    float mu  = s1 * (1.0f / CZ);
    float var = s2 * (1.0f / CZ) - mu * mu;
    float rstd = rsqrtf(var + 1e-5f);
    float y0 = (x0 - mu) * rstd * lnw[lane]      + lnb[lane];
    float y1 = (x1 - mu) * rstd * lnw[64 + lane] + lnb[64 + lane];
    float4 wa0 = *(const float4*)&w_b[lane * 8];
    float4 wa1 = *(const float4*)&w_b[lane * 8 + 4];
    float4 wb0 = *(const float4*)&w_b[(64 + lane) * 8];
    float4 wb1 = *(const float4*)&w_b[(64 + lane) * 8 + 4];
    float p[8];
    p[0] = y0 * wa0.x + y1 * wb0.x;
    p[1] = y0 * wa0.y + y1 * wb0.y;
    p[2] = y0 * wa0.z + y1 * wb0.z;
    p[3] = y0 * wa0.w + y1 * wb0.w;
    p[4] = y0 * wa1.x + y1 * wb1.x;
    p[5] = y0 * wa1.y + y1 * wb1.y;
    p[6] = y0 * wa1.z + y1 * wb1.z;
    p[7] = y0 * wa1.w + y1 * wb1.w;
    #pragma unroll
    for (int off = 32; off; off >>= 1) {
        #pragma unroll
        for (int h = 0; h < 8; h++) p[h] += __shfl_xor(p[h], off);
    }
    if (lane == 0) {
        float mt = mterm[j];
        #pragma unroll
        for (int h = 0; h < 8; h++)
            wbl[((size_t)h * NN + i) * NN + j] = f2bf(p[h] + mt);
    }
}

// ---------------- k3: softmax over j, bf16 in place on wbl[h][i][:] ----------------
__global__ __launch_bounds__(256) void k3_softmax(unsigned short* __restrict__ wbl)
{
    const int tid = threadIdx.x, wave = tid >> 6, lane = tid & 63;
    const int row = blockIdx.x * 4 + wave;   // = h*384 + i
    unsigned short* p = wbl + (size_t)row * NN;
    float x[6];
    float mx = -1e30f;
    #pragma unroll
    for (int e = 0; e < 6; e++) { x[e] = bf2f(p[lane + e * 64]); mx = fmaxf(mx, x[e]); }
    #pragma unroll
    for (int off = 32; off; off >>= 1) mx = fmaxf(mx, __shfl_xor(mx, off));
    float sum = 0.f;
    #pragma unroll
    for (int e = 0; e < 6; e++) { x[e] = expf(x[e] - mx); sum += x[e]; }
    #pragma unroll
    for (int off = 32; off; off >>= 1) sum += __shfl_xor(sum, off);
    float inv = 1.0f / sum;
    #pragma unroll
    for (int e = 0; e < 6; e++) p[lane + e * 64] = f2bf(x[e] * inv);
}

// ---------------- k4: per-h MFMA GEMM  o[i][sc] = W[h] (384x384) x vT[h]^T (384x8192) ----------------
// 128x128 tile, BK=32, 4 waves (2x2), each wave 64x64 = 4x4 fragments of 16x16x32 bf16.
__global__ __launch_bounds__(256) void k4_mfma(
    const unsigned short* __restrict__ wbf, const unsigned short* __restrict__ vT,
    unsigned short* __restrict__ ob)
{
    __shared__ unsigned short Al[128 * 32];   // A tile  [i-rows][k]
    __shared__ unsigned short Bl[128 * 32];   // B^T tile [n-rows][k]
    const int tid  = threadIdx.x;
    const int wid  = tid >> 6, lane = tid & 63;
    const int wm   = wid >> 1, wn = wid & 1;
    const int h    = blockIdx.z;
    const int i0   = blockIdx.y * 128;
    const int n0   = blockIdx.x * 128;
    const unsigned short* Ag = wbf + (size_t)h * NN * NN;       // [384][384]
    const unsigned short* Bg = vT  + (size_t)h * 8192 * NN;     // [8192][384]

    f32x4 acc[4][4] = {};

    const int lrow = lane >> 2, lchunk = lane & 3;   // staging: 16 rows x 4 chunks of 16B per issue
    for (int k0 = 0; k0 < NN; k0 += 32) {
        #pragma unroll
        for (int q = 0; q < 2; q++) {
            int issue = wid * 2 + q;                  // 0..7 -> rows [issue*16, +16)
            int r = issue * 16 + lrow;
            gload_lds16(Ag + (size_t)(i0 + r) * NN + k0 + lchunk * 8,
                        (void*)((char*)Al + issue * 1024));
            gload_lds16(Bg + (size_t)(n0 + r) * NN + k0 + lchunk * 8,
                        (void*)((char*)Bl + issue * 1024));
        }
        __syncthreads();   // drains vmcnt + barrier

        short8v a[4], b[4];
        #pragma unroll
        for (int mi = 0; mi < 4; mi++)
            a[mi] = *(const short8v*)&Al[(wm * 64 + mi * 16 + (lane & 15)) * 32 + (lane >> 4) * 8];
        #pragma unroll
        for (int ni = 0; ni < 4; ni++)
            b[ni] = *(const short8v*)&Bl[(wn * 64 + ni * 16 + (lane & 15)) * 32 + (lane >> 4) * 8];
        #pragma unroll
        for (int mi = 0; mi < 4; mi++)
            #pragma unroll
            for (int ni = 0; ni < 4; ni++)
                acc[mi][ni] = __builtin_amdgcn_mfma_f32_16x16x32_bf16(a[mi], b[ni], acc[mi][ni], 0, 0, 0);
        __syncthreads();
    }

    // C/D layout: col = lane&15, row = (lane>>4)*4 + reg   -> i = row-dim, n = col-dim
    #pragma unroll
    for (int mi = 0; mi < 4; mi++) {
        const int ibase = i0 + wm * 64 + mi * 16 + ((lane >> 4) << 2);
        #pragma unroll
        for (int ni = 0; ni < 4; ni++) {
            const int n = n0 + wn * 64 + ni * 16 + (lane & 15);
            const int s = n >> 5, c = n & 31;
            #pragma unroll
            for (int r = 0; r < 4; r++)
                ob[((size_t)s * NN + (ibase + r)) * HC + (h << 5) + c] = f2bf(acc[mi][ni][r]);
        }
    }
}

// ---------------- k5: out[98304,64] = (o .* g)[98304,256] @ w_out[256,64]  via MFMA ----------------
// 4 waves/block, each wave 16 rows x 64 cols, K=256 in 8 ksteps. A-frags straight from
// global (each o/g element read+multiplied exactly once); B = w_out^T in LDS, XOR-swizzled.
__global__ __launch_bounds__(256) void k5_mfma(
    const unsigned short* __restrict__ ob, const unsigned short* __restrict__ g,
    const float* __restrict__ w_out, float* __restrict__ out)
{
    __shared__ unsigned short WT[64 * 256];   // w_out^T bf16, 32 KB, swizzled: idx ^ ((c&7)<<3)
    const int tid = threadIdx.x, wid = tid >> 6, lane = tid & 63;
    #pragma unroll
    for (int e = 0; e < 16; e++) {
        int fidx = (tid + e * 256) * 4;
        float4 w4 = *(const float4*)&w_out[fidx];
        int k = fidx >> 6, c0 = fidx & 63;
        float wv[4] = {w4.x, w4.y, w4.z, w4.w};
        #pragma unroll
        for (int q = 0; q < 4; q++) {
            int c = c0 + q;
            WT[(((c << 8) + k)) ^ ((c & 7) << 3)] = f2bf(wv[q]);
        }
    }
    __syncthreads();

    const size_t rowbase = (size_t)blockIdx.x * 64 + wid * 16;
    const int arow = lane & 15, achunk = lane >> 4;
    const unsigned short* op = ob + (rowbase + arow) * HC + achunk * 8;
    const unsigned short* gp = g  + (rowbase + arow) * HC + achunk * 8;

    f32x4 acc[4] = {};
    #pragma unroll
    for (int ks = 0; ks < 8; ks++) {
        ushort8v o8 = *(const ushort8v*)(op + ks * 32);
        ushort8v g8 = *(const ushort8v*)(gp + ks * 32);
        short8v a;
        #pragma unroll
        for (int q = 0; q < 8; q++)
            a[q] = (short)f2bf(bf2f(o8[q]) * bf2f(g8[q]));
        #pragma unroll
        for (int nf = 0; nf < 4; nf++) {
            const int c = nf * 16 + arow;    // b-frag col
            short8v b = *(const short8v*)&WT[(((c << 8) + ks * 32 + achunk * 8)) ^ ((c & 7) << 3)];
            acc[nf] = __builtin_amdgcn_mfma_f32_16x16x32_bf16(a, b, acc[nf], 0, 0, 0);
        }
    }
    // D: col = lane&15, row = achunk*4 + r
    #pragma unroll
    for (int nf = 0; nf < 4; nf++)
        #pragma unroll
        for (int r = 0; r < 4; r++)
            out[(rowbase + achunk * 4 + r) * CM + nf * 16 + arow] = acc[nf][r];
}

extern "C" void kernel_launch(void* const* d_in, const int* in_sizes, int n_in,
                              void* d_out, int out_size, void* d_ws, size_t ws_size,
                              hipStream_t stream)
{
    const float* m      = (const float*)d_in[0];
    const float* z      = (const float*)d_in[1];
    const unsigned int* mask_raw = (const unsigned int*)d_in[2];
    const float* ln_m_w = (const float*)d_in[3];
    const float* ln_m_b = (const float*)d_in[4];
    const float* ln_z_w = (const float*)d_in[5];
    const float* ln_z_b = (const float*)d_in[6];
    const float* w_v    = (const float*)d_in[7];
    const float* w_b    = (const float*)d_in[8];
    const float* w_g    = (const float*)d_in[9];
    const float* w_out  = (const float*)d_in[10];
    float* out = (float*)d_out;

    // ws: mterm f32[384] | wbl bf16[1179648] | vT bf16[NV] | g bf16[NV] | ob bf16[NV]
    float* mterm = (float*)d_ws;
    unsigned short* wbl = (unsigned short*)(mterm + 384);
    unsigned short* vT  = wbl + 1179648;
    unsigned short* g   = vT + NV;
    unsigned short* ob  = g + NV;

    k0_mask<<<1, 384, 0, stream>>>(mask_raw, mterm);
    k1_lnm_vg<<<6144, 256, 0, stream>>>(m, ln_m_w, ln_m_b, w_v, w_g, vT, g);
    k2_lnz_b<<<36864, 256, 0, stream>>>(z, ln_z_w, ln_z_b, w_b, mterm, wbl);
    k3_softmax<<<768, 256, 0, stream>>>(wbl);
    k4_mfma<<<dim3(64, 3, 8), 256, 0, stream>>>(wbl, vT, ob);
    k5_mfma<<<1536, 256, 0, stream>>>(ob, g, w_out, out);
}

// Round 7
// 223.972 us; speedup vs baseline: 2.8365x; 1.3378x over previous
//
#include <hip/hip_runtime.h>
#include <math.h>

// MSAPairWeightedAveraging — round 6: k1 -> fused LN + dual MFMA GEMM (v,g) with
// LDS-staged coalesced epilogue. S=256, N=384, C_M=64, C_Z=128, C=32, H=8, H*C=256.
// ws: mterm f32[384] | wbl bf16[8,384,384] | vT bf16[8,8192,384] | g bf16[98304,256]
//     | ob bf16[98304,256] | BTg bf16[512,64] (pre-swizzled weights)

#define SS 256
#define NN 384
#define CM 64
#define CZ 128
#define HH 8
#define HC 256
#define NV 25165824   // S*N*HC

typedef __attribute__((ext_vector_type(8))) short short8v;
typedef __attribute__((ext_vector_type(8))) unsigned short ushort8v;
typedef __attribute__((ext_vector_type(4))) unsigned short ushort4v;
typedef __attribute__((ext_vector_type(4))) float f32x4;

static __device__ __forceinline__ float bf2f(unsigned short u) {
    union { unsigned int i; float f; } x; x.i = ((unsigned int)u) << 16; return x.f;
}
static __device__ __forceinline__ unsigned short f2bf(float f) {
    union { float f; unsigned int i; } x; x.f = f;
    unsigned int r = x.i + 0x7FFFu + ((x.i >> 16) & 1u);   // RNE
    return (unsigned short)(r >> 16);
}
static __device__ __forceinline__ void gload_lds16(const void* g, void* l) {
    __builtin_amdgcn_global_load_lds((const __attribute__((address_space(1))) void*)g,
                                     (__attribute__((address_space(3))) void*)l, 16, 0, 0);
}

// ---------------- k0: decode single_mask (uint8 / int32 / float32) -> mterm[384] ----------------
__global__ __launch_bounds__(384) void k0_mask(const unsigned int* __restrict__ mu,
                                               float* __restrict__ mterm)
{
    __shared__ int byteLayout;
    if (threadIdx.x == 0) byteLayout = 0;
    __syncthreads();
    if (threadIdx.x < 96) {
        unsigned int u = mu[threadIdx.x];
        if (u != 0u && u != 1u && u != 0x3F800000u) atomicOr(&byteLayout, 1);
    }
    __syncthreads();
    const int j = threadIdx.x;
    int val;
    if (byteLayout) val = ((const unsigned char*)mu)[j];
    else            val = (mu[j] != 0u);
    mterm[j] = val ? 0.0f : -1e9f;
}

// ---------------- k1a: transpose [w_v|w_g] fp32 [64][256] -> BTg bf16 [512 cols][64 k], swizzled ----------------
__global__ __launch_bounds__(256) void k1a_stageB(
    const float* __restrict__ w_v, const float* __restrict__ w_g,
    unsigned short* __restrict__ BTg)
{
    const int col = blockIdx.x * 4 + (threadIdx.x >> 6);
    const int k   = threadIdx.x & 63;
    float w = (col < 256) ? w_v[k * 256 + col] : w_g[k * 256 + (col - 256)];
    BTg[col * 64 + (k ^ ((col & 7) << 3))] = f2bf(w);
}

// ---------------- k1: LN(m) + MFMA -> vT[h][(s,c)][j] bf16, g[(s,n)][hc] bf16 ----------------
// 64 rows/block, 4 waves col-split over 512 output cols (0-255 = v, 256-511 = g).
__global__ __launch_bounds__(256, 2) void k1_lnm_vg(
    const float* __restrict__ m, const float* __restrict__ lnw, const float* __restrict__ lnb,
    const unsigned short* __restrict__ BTg,
    unsigned short* __restrict__ vT, unsigned short* __restrict__ gout)
{
    __shared__ unsigned short smem[37888];   // Al[4096] | BT[32768] / (VS_v[16384] | VS_g[17408])
    unsigned short* Al   = smem;             // [64 rows][64 k], swizzled
    unsigned short* BT   = smem + 4096;      // [512 cols][64 k], swizzled (linear copy of BTg)
    unsigned short* VS_v = smem + 4096;      // [256 hc][64 j], swizzled (overlays BT)
    unsigned short* VS_g = smem + 20480;     // [64 j][272 pad], row stride 272

    const int tid = threadIdx.x, wid = tid >> 6, lane = tid & 63;
    const int rl = lane & 15, kc = lane >> 4;
    const int rowBase = blockIdx.x * 64;     // rows = s*384 + j, 64 j within one s
    const int s  = rowBase / NN;
    const int j0 = rowBase - s * NN;

    // 1) stage BT (64 KB) via global_load_lds, linear
    #pragma unroll
    for (int it = 0; it < 16; it++) {
        int eoff = it * 2048 + wid * 512;    // elems
        gload_lds16(BTg + eoff + lane * 8, (void*)((char*)BT + eoff * 2));
    }

    // 2) LN of 16 rows per wave -> Al (bf16, swizzled)
    const float lw = lnw[lane], lb = lnb[lane];
    for (int rr = 0; rr < 16; rr++) {
        int row = wid * 16 + rr;
        float x = m[(size_t)(rowBase + row) * CM + lane];
        float s1 = x, s2 = x * x;
        #pragma unroll
        for (int off = 32; off; off >>= 1) {
            s1 += __shfl_xor(s1, off);
            s2 += __shfl_xor(s2, off);
        }
        float mu  = s1 * (1.0f / CM);
        float var = s2 * (1.0f / CM) - mu * mu;
        float y = (x - mu) * rsqrtf(var + 1e-5f) * lw + lb;
        Al[row * 64 + (lane ^ ((row & 7) << 3))] = f2bf(y);
    }
    __syncthreads();   // drains gload_lds vmcnt + Al writes

    // 3) MFMA: this wave computes all 64 rows x its 128 cols (8 n-frags), K=64 (2 ksteps)
    f32x4 acc[4][8] = {};
    #pragma unroll
    for (int ks = 0; ks < 2; ks++) {
        short8v a[4];
        #pragma unroll
        for (int mi = 0; mi < 4; mi++) {
            int row = mi * 16 + rl;
            a[mi] = *(const short8v*)&Al[(row * 64 + ks * 32 + kc * 8) ^ ((row & 7) << 3)];
        }
        #pragma unroll
        for (int nf = 0; nf < 8; nf++) {
            int col = wid * 128 + nf * 16 + rl;
            short8v b = *(const short8v*)&BT[(col * 64 + ks * 32 + kc * 8) ^ ((col & 7) << 3)];
            #pragma unroll
            for (int mi = 0; mi < 4; mi++)
                acc[mi][nf] = __builtin_amdgcn_mfma_f32_16x16x32_bf16(a[mi], b, acc[mi][nf], 0, 0, 0);
        }
    }
    __syncthreads();   // BT dead; safe to overlay with VS

    // 4) epilogue into LDS staging. D: col = nf*16+rl, row = mi*16 + kc*4 + r
    if (wid < 2) {
        #pragma unroll
        for (int mi = 0; mi < 4; mi++) {
            int jb = mi * 16 + kc * 4;
            #pragma unroll
            for (int nf = 0; nf < 8; nf++) {
                int hc = wid * 128 + nf * 16 + rl;
                ushort4v p;
                #pragma unroll
                for (int r = 0; r < 4; r++) p[r] = f2bf(acc[mi][nf][r]);
                *(ushort4v*)&VS_v[(hc * 64 + jb) ^ ((hc & 7) << 3)] = p;
            }
        }
    } else {
        #pragma unroll
        for (int mi = 0; mi < 4; mi++) {
            int jb = mi * 16 + kc * 4;
            #pragma unroll
            for (int nf = 0; nf < 8; nf++) {
                int hc = (wid - 2) * 128 + nf * 16 + rl;
                #pragma unroll
                for (int r = 0; r < 4; r++) {
                    float sg = 1.0f / (1.0f + expf(-acc[mi][nf][r]));
                    VS_g[(jb + r) * 272 + hc] = f2bf(sg);
                }
            }
        }
    }
    __syncthreads();

    // 5) coalesced copy-out. v: 256 hc-rows x 64 j
    #pragma unroll
    for (int p = 0; p < 8; p++) {
        int hc = p * 32 + (tid >> 3);
        int jc = (tid & 7) * 8;
        ushort8v val = *(const ushort8v*)&VS_v[(hc * 64 + jc) ^ ((hc & 7) << 3)];
        size_t vtoff = ((size_t)((hc >> 5) * 8192 + s * 32 + (hc & 31))) * NN + j0 + jc;
        *(ushort8v*)&vT[vtoff] = val;
    }
    // g: 64 rows x 256 hc, fully linear
    #pragma unroll
    for (int p = 0; p < 8; p++) {
        int row = p * 8 + (tid >> 5);
        int hc0 = (tid & 31) * 8;
        ushort8v val = *(const ushort8v*)&VS_g[row * 272 + hc0];
        *(ushort8v*)&gout[(size_t)(rowBase + row) * HC + hc0] = val;
    }
}

// ---------------- k2: LN(z) @ w_b + mask -> logits bf16 wbl[h][i][j] ----------------
__global__ __launch_bounds__(256) void k2_lnz_b(
    const float* __restrict__ z, const float* __restrict__ lnw, const float* __restrict__ lnb,
    const float* __restrict__ w_b, const float* __restrict__ mterm, unsigned short* __restrict__ wbl)
{
    const int tid = threadIdx.x, wave = tid >> 6, lane = tid & 63;
    const int row = blockIdx.x * 4 + wave;          // = i*384 + j
    const int i = row / NN, j = row - i * NN;
    const float* zp = z + (size_t)row * CZ;
    float x0 = zp[lane], x1 = zp[64 + lane];
    float s1 = x0 + x1, s2 = x0 * x0 + x1 * x1;
    #pragma unroll
    for (int off = 32; off; off >>= 1) {
        s1 += __shfl_xor(s1, off);
        s2 += __shfl_xor(s2, off);
    }
    float mu  = s1 * (1.0f / CZ);
    float var = s2 * (1.0f / CZ) - mu * mu;
    float rstd = rsqrtf(var + 1e-5f);
    float y0 = (x0 - mu) * rstd * lnw[lane]      + lnb[lane];
    float y1 = (x1 - mu) * rstd * lnw[64 + lane] + lnb[64 + lane];
    float4 wa0 = *(const float4*)&w_b[lane * 8];
    float4 wa1 = *(const float4*)&w_b[lane * 8 + 4];
    float4 wb0 = *(const float4*)&w_b[(64 + lane) * 8];
    float4 wb1 = *(const float4*)&w_b[(64 + lane) * 8 + 4];
    float p[8];
    p[0] = y0 * wa0.x + y1 * wb0.x;
    p[1] = y0 * wa0.y + y1 * wb0.y;
    p[2] = y0 * wa0.z + y1 * wb0.z;
    p[3] = y0 * wa0.w + y1 * wb0.w;
    p[4] = y0 * wa1.x + y1 * wb1.x;
    p[5] = y0 * wa1.y + y1 * wb1.y;
    p[6] = y0 * wa1.z + y1 * wb1.z;
    p[7] = y0 * wa1.w + y1 * wb1.w;
    #pragma unroll
    for (int off = 32; off; off >>= 1) {
        #pragma unroll
        for (int h = 0; h < 8; h++) p[h] += __shfl_xor(p[h], off);
    }
    if (lane == 0) {
        float mt = mterm[j];
        #pragma unroll
        for (int h = 0; h < 8; h++)
            wbl[((size_t)h * NN + i) * NN + j] = f2bf(p[h] + mt);
    }
}

// ---------------- k3: softmax over j, bf16 in place on wbl[h][i][:] ----------------
__global__ __launch_bounds__(256) void k3_softmax(unsigned short* __restrict__ wbl)
{
    const int tid = threadIdx.x, wave = tid >> 6, lane = tid & 63;
    const int row = blockIdx.x * 4 + wave;   // = h*384 + i
    unsigned short* p = wbl + (size_t)row * NN;
    float x[6];
    float mx = -1e30f;
    #pragma unroll
    for (int e = 0; e < 6; e++) { x[e] = bf2f(p[lane + e * 64]); mx = fmaxf(mx, x[e]); }
    #pragma unroll
    for (int off = 32; off; off >>= 1) mx = fmaxf(mx, __shfl_xor(mx, off));
    float sum = 0.f;
    #pragma unroll
    for (int e = 0; e < 6; e++) { x[e] = expf(x[e] - mx); sum += x[e]; }
    #pragma unroll
    for (int off = 32; off; off >>= 1) sum += __shfl_xor(sum, off);
    float inv = 1.0f / sum;
    #pragma unroll
    for (int e = 0; e < 6; e++) p[lane + e * 64] = f2bf(x[e] * inv);
}

// ---------------- k4: per-h MFMA GEMM  o[i][sc] = W[h] (384x384) x vT[h]^T (384x8192) ----------------
__global__ __launch_bounds__(256) void k4_mfma(
    const unsigned short* __restrict__ wbf, const unsigned short* __restrict__ vT,
    unsigned short* __restrict__ ob)
{
    __shared__ unsigned short Al[128 * 32];
    __shared__ unsigned short Bl[128 * 32];
    const int tid  = threadIdx.x;
    const int wid  = tid >> 6, lane = tid & 63;
    const int wm   = wid >> 1, wn = wid & 1;
    const int h    = blockIdx.z;
    const int i0   = blockIdx.y * 128;
    const int n0   = blockIdx.x * 128;
    const unsigned short* Ag = wbf + (size_t)h * NN * NN;
    const unsigned short* Bg = vT  + (size_t)h * 8192 * NN;

    f32x4 acc[4][4] = {};

    const int lrow = lane >> 2, lchunk = lane & 3;
    for (int k0 = 0; k0 < NN; k0 += 32) {
        #pragma unroll
        for (int q = 0; q < 2; q++) {
            int issue = wid * 2 + q;
            int r = issue * 16 + lrow;
            gload_lds16(Ag + (size_t)(i0 + r) * NN + k0 + lchunk * 8,
                        (void*)((char*)Al + issue * 1024));
            gload_lds16(Bg + (size_t)(n0 + r) * NN + k0 + lchunk * 8,
                        (void*)((char*)Bl + issue * 1024));
        }
        __syncthreads();

        short8v a[4], b[4];
        #pragma unroll
        for (int mi = 0; mi < 4; mi++)
            a[mi] = *(const short8v*)&Al[(wm * 64 + mi * 16 + (lane & 15)) * 32 + (lane >> 4) * 8];
        #pragma unroll
        for (int ni = 0; ni < 4; ni++)
            b[ni] = *(const short8v*)&Bl[(wn * 64 + ni * 16 + (lane & 15)) * 32 + (lane >> 4) * 8];
        #pragma unroll
        for (int mi = 0; mi < 4; mi++)
            #pragma unroll
            for (int ni = 0; ni < 4; ni++)
                acc[mi][ni] = __builtin_amdgcn_mfma_f32_16x16x32_bf16(a[mi], b[ni], acc[mi][ni], 0, 0, 0);
        __syncthreads();
    }

    #pragma unroll
    for (int mi = 0; mi < 4; mi++) {
        const int ibase = i0 + wm * 64 + mi * 16 + ((lane >> 4) << 2);
        #pragma unroll
        for (int ni = 0; ni < 4; ni++) {
            const int n = n0 + wn * 64 + ni * 16 + (lane & 15);
            const int s = n >> 5, c = n & 31;
            #pragma unroll
            for (int r = 0; r < 4; r++)
                ob[((size_t)s * NN + (ibase + r)) * HC + (h << 5) + c] = f2bf(acc[mi][ni][r]);
        }
    }
}

// ---------------- k5: out[98304,64] = (o .* g)[98304,256] @ w_out[256,64]  via MFMA ----------------
__global__ __launch_bounds__(256) void k5_mfma(
    const unsigned short* __restrict__ ob, const unsigned short* __restrict__ g,
    const float* __restrict__ w_out, float* __restrict__ out)
{
    __shared__ unsigned short WT[64 * 256];   // w_out^T bf16, swizzled: idx ^ ((c&7)<<3)
    const int tid = threadIdx.x, wid = tid >> 6, lane = tid & 63;
    #pragma unroll
    for (int e = 0; e < 16; e++) {
        int fidx = (tid + e * 256) * 4;
        float4 w4 = *(const float4*)&w_out[fidx];
        int k = fidx >> 6, c0 = fidx & 63;
        float wv[4] = {w4.x, w4.y, w4.z, w4.w};
        #pragma unroll
        for (int q = 0; q < 4; q++) {
            int c = c0 + q;
            WT[(((c << 8) + k)) ^ ((c & 7) << 3)] = f2bf(wv[q]);
        }
    }
    __syncthreads();

    const size_t rowbase = (size_t)blockIdx.x * 64 + wid * 16;
    const int arow = lane & 15, achunk = lane >> 4;
    const unsigned short* op = ob + (rowbase + arow) * HC + achunk * 8;
    const unsigned short* gp = g  + (rowbase + arow) * HC + achunk * 8;

    f32x4 acc[4] = {};
    #pragma unroll
    for (int ks = 0; ks < 8; ks++) {
        ushort8v o8 = *(const ushort8v*)(op + ks * 32);
        ushort8v g8 = *(const ushort8v*)(gp + ks * 32);
        short8v a;
        #pragma unroll
        for (int q = 0; q < 8; q++)
            a[q] = (short)f2bf(bf2f(o8[q]) * bf2f(g8[q]));
        #pragma unroll
        for (int nf = 0; nf < 4; nf++) {
            const int c = nf * 16 + arow;
            short8v b = *(const short8v*)&WT[(((c << 8) + ks * 32 + achunk * 8)) ^ ((c & 7) << 3)];
            acc[nf] = __builtin_amdgcn_mfma_f32_16x16x32_bf16(a, b, acc[nf], 0, 0, 0);
        }
    }
    #pragma unroll
    for (int nf = 0; nf < 4; nf++)
        #pragma unroll
        for (int r = 0; r < 4; r++)
            out[(rowbase + achunk * 4 + r) * CM + nf * 16 + arow] = acc[nf][r];
}

extern "C" void kernel_launch(void* const* d_in, const int* in_sizes, int n_in,
                              void* d_out, int out_size, void* d_ws, size_t ws_size,
                              hipStream_t stream)
{
    const float* m      = (const float*)d_in[0];
    const float* z      = (const float*)d_in[1];
    const unsigned int* mask_raw = (const unsigned int*)d_in[2];
    const float* ln_m_w = (const float*)d_in[3];
    const float* ln_m_b = (const float*)d_in[4];
    const float* ln_z_w = (const float*)d_in[5];
    const float* ln_z_b = (const float*)d_in[6];
    const float* w_v    = (const float*)d_in[7];
    const float* w_b    = (const float*)d_in[8];
    const float* w_g    = (const float*)d_in[9];
    const float* w_out  = (const float*)d_in[10];
    float* out = (float*)d_out;

    // ws: mterm f32[384] | wbl bf16[1179648] | vT bf16[NV] | g bf16[NV] | ob bf16[NV] | BTg bf16[32768]
    float* mterm = (float*)d_ws;
    unsigned short* wbl = (unsigned short*)(mterm + 384);
    unsigned short* vT  = wbl + 1179648;
    unsigned short* g   = vT + NV;
    unsigned short* ob  = g + NV;
    unsigned short* BTg = ob + NV;

    k0_mask<<<1, 384, 0, stream>>>(mask_raw, mterm);
    k1a_stageB<<<128, 256, 0, stream>>>(w_v, w_g, BTg);
    k1_lnm_vg<<<1536, 256, 0, stream>>>(m, ln_m_w, ln_m_b, BTg, vT, g);
    k2_lnz_b<<<36864, 256, 0, stream>>>(z, ln_z_w, ln_z_b, w_b, mterm, wbl);
    k3_softmax<<<768, 256, 0, stream>>>(wbl);
    k4_mfma<<<dim3(64, 3, 8), 256, 0, stream>>>(wbl, vT, ob);
    k5_mfma<<<1536, 256, 0, stream>>>(ob, g, w_out, out);
}

// Round 8
// 213.350 us; speedup vs baseline: 2.9777x; 1.0498x over previous
//
#include <hip/hip_runtime.h>
#include <math.h>

// MSAPairWeightedAveraging — round 7: m-path split into k1n (LN -> bf16, pre-swizzled)
// + k1b (dual-family 40KB-LDS MFMA GEMM for v^T and g). S=256, N=384, C_M=64, C_Z=128,
// C=32, H=8, H*C=256.
// ws: mterm f32[384] | wbl bf16[8,384,384] | vT bf16[8,8192,384] | g bf16[98304,256]
//     | ob bf16[98304,256] (k1 phase: aliased as mln bf16[98304,64]) | BTg bf16[512,64]

#define SS 256
#define NN 384
#define CM 64
#define CZ 128
#define HH 8
#define HC 256
#define NV 25165824   // S*N*HC

typedef __attribute__((ext_vector_type(8))) short short8v;
typedef __attribute__((ext_vector_type(8))) unsigned short ushort8v;
typedef __attribute__((ext_vector_type(4))) float f32x4;

static __device__ __forceinline__ float bf2f(unsigned short u) {
    union { unsigned int i; float f; } x; x.i = ((unsigned int)u) << 16; return x.f;
}
static __device__ __forceinline__ unsigned short f2bf(float f) {
    union { float f; unsigned int i; } x; x.f = f;
    unsigned int r = x.i + 0x7FFFu + ((x.i >> 16) & 1u);   // RNE
    return (unsigned short)(r >> 16);
}
static __device__ __forceinline__ void gload_lds16(const void* g, void* l) {
    __builtin_amdgcn_global_load_lds((const __attribute__((address_space(1))) void*)g,
                                     (__attribute__((address_space(3))) void*)l, 16, 0, 0);
}

// ---------------- k0: decode single_mask (uint8 / int32 / float32) -> mterm[384] ----------------
__global__ __launch_bounds__(384) void k0_mask(const unsigned int* __restrict__ mu,
                                               float* __restrict__ mterm)
{
    __shared__ int byteLayout;
    if (threadIdx.x == 0) byteLayout = 0;
    __syncthreads();
    if (threadIdx.x < 96) {
        unsigned int u = mu[threadIdx.x];
        if (u != 0u && u != 1u && u != 0x3F800000u) atomicOr(&byteLayout, 1);
    }
    __syncthreads();
    const int j = threadIdx.x;
    int val;
    if (byteLayout) val = ((const unsigned char*)mu)[j];
    else            val = (mu[j] != 0u);
    mterm[j] = val ? 0.0f : -1e9f;
}

// ---------------- k1a: transpose [w_v|w_g] fp32 [64][256] -> BTg bf16 [512 cols][64 k], swizzled ----------------
__global__ __launch_bounds__(256) void k1a_stageB(
    const float* __restrict__ w_v, const float* __restrict__ w_g,
    unsigned short* __restrict__ BTg)
{
    const int col = blockIdx.x * 4 + (threadIdx.x >> 6);
    const int k   = threadIdx.x & 63;
    float w = (col < 256) ? w_v[k * 256 + col] : w_g[k * 256 + (col - 256)];
    BTg[col * 64 + (k ^ ((col & 7) << 3))] = f2bf(w);
}

// ---------------- k1n: LN(m) -> mln bf16 [98304][64], pre-swizzled within rows ----------------
__global__ __launch_bounds__(256) void k1n_ln(
    const float* __restrict__ m, const float* __restrict__ lnw, const float* __restrict__ lnb,
    unsigned short* __restrict__ mln)
{
    const int tid = threadIdx.x, wid = tid >> 6, lane = tid & 63;
    const int rowBase = blockIdx.x * 64 + wid * 16;
    const float lw = lnw[lane], lb = lnb[lane];
    #pragma unroll 4
    for (int rr = 0; rr < 16; rr++) {
        int row = rowBase + rr;
        float x = m[(size_t)row * CM + lane];
        float s1 = x, s2 = x * x;
        #pragma unroll
        for (int off = 32; off; off >>= 1) {
            s1 += __shfl_xor(s1, off);
            s2 += __shfl_xor(s2, off);
        }
        float mu  = s1 * (1.0f / CM);
        float var = s2 * (1.0f / CM) - mu * mu;
        float y = (x - mu) * rsqrtf(var + 1e-5f) * lw + lb;
        mln[(size_t)row * CM + (lane ^ ((row & 7) << 3))] = f2bf(y);
    }
}

// ---------------- k1b: GEMM mln[64k] x {w_v,w_g}[64k,256] per 64-row tile ----------------
// grid (1536, 2): blockIdx.y = family (0: v^T output, 1: sigmoid->g output).
// LDS 40KB -> 4 blocks/CU. W and A staged linear via global_load_lds, XOR-read.
__global__ __launch_bounds__(256) void k1b_vg(
    const unsigned short* __restrict__ BTg, const unsigned short* __restrict__ mln,
    unsigned short* __restrict__ vT, unsigned short* __restrict__ gout)
{
    __shared__ unsigned short Wl[16384];  // [256 cols][64 k] swizzled
    __shared__ unsigned short Al[4096];   // [64 rows][64 k] swizzled
    const int tid = threadIdx.x, wid = tid >> 6, lane = tid & 63;
    const int rl = lane & 15, kc = lane >> 4;
    const int rowBase = blockIdx.x * 64;       // 64 | 384 -> never straddles s
    const int s = rowBase / NN, j0 = rowBase - s * NN;
    const int fam = blockIdx.y;

    #pragma unroll
    for (int it = 0; it < 8; it++) {
        int eoff = (wid * 8 + it) * 512;
        gload_lds16(BTg + fam * 16384 + eoff + lane * 8, (void*)((char*)Wl + eoff * 2));
    }
    #pragma unroll
    for (int it = 0; it < 2; it++) {
        int eoff = (wid * 2 + it) * 512;
        gload_lds16(mln + (size_t)rowBase * CM + eoff + lane * 8, (void*)((char*)Al + eoff * 2));
    }
    __syncthreads();   // drains gload_lds vmcnt + barrier

    f32x4 acc[4][4] = {};
    #pragma unroll
    for (int ks = 0; ks < 2; ks++) {
        short8v wf[4], al[4];
        #pragma unroll
        for (int q = 0; q < 4; q++) {
            int col = wid * 64 + q * 16 + rl;
            wf[q] = *(const short8v*)&Wl[(col * 64 + ks * 32 + kc * 8) ^ ((col & 7) << 3)];
            int row = q * 16 + rl;
            al[q] = *(const short8v*)&Al[(row * 64 + ks * 32 + kc * 8) ^ ((row & 7) << 3)];
        }
        if (fam == 0) {
            #pragma unroll
            for (int mi = 0; mi < 4; mi++)
                #pragma unroll
                for (int nf = 0; nf < 4; nf++)
                    acc[mi][nf] = __builtin_amdgcn_mfma_f32_16x16x32_bf16(wf[mi], al[nf], acc[mi][nf], 0, 0, 0);
        } else {
            #pragma unroll
            for (int mi = 0; mi < 4; mi++)
                #pragma unroll
                for (int nf = 0; nf < 4; nf++)
                    acc[mi][nf] = __builtin_amdgcn_mfma_f32_16x16x32_bf16(al[mi], wf[nf], acc[mi][nf], 0, 0, 0);
        }
    }

    if (fam == 0) {
        // D[i=hc][n=j]: hc = wid*64+mi*16+kc*4+r (reg dim), j = j0+nf*16+rl (lane dim)
        #pragma unroll
        for (int mi = 0; mi < 4; mi++)
            #pragma unroll
            for (int nf = 0; nf < 4; nf++) {
                int j = j0 + nf * 16 + rl;
                #pragma unroll
                for (int r = 0; r < 4; r++) {
                    int hc = wid * 64 + mi * 16 + kc * 4 + r;
                    size_t vrow = (size_t)((hc >> 5) * 8192 + s * 32 + (hc & 31));
                    vT[vrow * NN + j] = f2bf(acc[mi][nf][r]);
                }
            }
    } else {
        // D[i=row][n=hc]: row = rowBase+mi*16+kc*4+r, hc = wid*64+nf*16+rl
        #pragma unroll
        for (int mi = 0; mi < 4; mi++)
            #pragma unroll
            for (int nf = 0; nf < 4; nf++) {
                int hc = wid * 64 + nf * 16 + rl;
                #pragma unroll
                for (int r = 0; r < 4; r++) {
                    int row = rowBase + mi * 16 + kc * 4 + r;
                    float sg = 1.0f / (1.0f + expf(-acc[mi][nf][r]));
                    gout[(size_t)row * HC + hc] = f2bf(sg);
                }
            }
    }
}

// ---------------- k2: LN(z) @ w_b + mask -> logits bf16 wbl[h][i][j] ----------------
__global__ __launch_bounds__(256) void k2_lnz_b(
    const float* __restrict__ z, const float* __restrict__ lnw, const float* __restrict__ lnb,
    const float* __restrict__ w_b, const float* __restrict__ mterm, unsigned short* __restrict__ wbl)
{
    const int tid = threadIdx.x, wave = tid >> 6, lane = tid & 63;
    const int row = blockIdx.x * 4 + wave;          // = i*384 + j
    const int i = row / NN, j = row - i * NN;
    const float* zp = z + (size_t)row * CZ;
    float x0 = zp[lane], x1 = zp[64 + lane];
    float s1 = x0 + x1, s2 = x0 * x0 + x1 * x1;
    #pragma unroll
    for (int off = 32; off; off >>= 1) {
        s1 += __shfl_xor(s1, off);
        s2 += __shfl_xor(s2, off);
    }
    float mu  = s1 * (1.0f / CZ);
    float var = s2 * (1.0f / CZ) - mu * mu;
    float rstd = rsqrtf(var + 1e-5f);
    float y0 = (x0 - mu) * rstd * lnw[lane]      + lnb[lane];
    float y1 = (x1 - mu) * rstd * lnw[64 + lane] + lnb[64 + lane];
    float4 wa0 = *(const float4*)&w_b[lane * 8];
    float4 wa1 = *(const float4*)&w_b[lane * 8 + 4];
    float4 wb0 = *(const float4*)&w_b[(64 + lane) * 8];
    float4 wb1 = *(const float4*)&w_b[(64 + lane) * 8 + 4];
    float p[8];
    p[0] = y0 * wa0.x + y1 * wb0.x;
    p[1] = y0 * wa0.y + y1 * wb0.y;
    p[2] = y0 * wa0.z + y1 * wb0.z;
    p[3] = y0 * wa0.w + y1 * wb0.w;
    p[4] = y0 * wa1.x + y1 * wb1.x;
    p[5] = y0 * wa1.y + y1 * wb1.y;
    p[6] = y0 * wa1.z + y1 * wb1.z;
    p[7] = y0 * wa1.w + y1 * wb1.w;
    #pragma unroll
    for (int off = 32; off; off >>= 1) {
        #pragma unroll
        for (int h = 0; h < 8; h++) p[h] += __shfl_xor(p[h], off);
    }
    if (lane == 0) {
        float mt = mterm[j];
        #pragma unroll
        for (int h = 0; h < 8; h++)
            wbl[((size_t)h * NN + i) * NN + j] = f2bf(p[h] + mt);
    }
}

// ---------------- k3: softmax over j, bf16 in place on wbl[h][i][:] ----------------
__global__ __launch_bounds__(256) void k3_softmax(unsigned short* __restrict__ wbl)
{
    const int tid = threadIdx.x, wave = tid >> 6, lane = tid & 63;
    const int row = blockIdx.x * 4 + wave;   // = h*384 + i
    unsigned short* p = wbl + (size_t)row * NN;
    float x[6];
    float mx = -1e30f;
    #pragma unroll
    for (int e = 0; e < 6; e++) { x[e] = bf2f(p[lane + e * 64]); mx = fmaxf(mx, x[e]); }
    #pragma unroll
    for (int off = 32; off; off >>= 1) mx = fmaxf(mx, __shfl_xor(mx, off));
    float sum = 0.f;
    #pragma unroll
    for (int e = 0; e < 6; e++) { x[e] = expf(x[e] - mx); sum += x[e]; }
    #pragma unroll
    for (int off = 32; off; off >>= 1) sum += __shfl_xor(sum, off);
    float inv = 1.0f / sum;
    #pragma unroll
    for (int e = 0; e < 6; e++) p[lane + e * 64] = f2bf(x[e] * inv);
}

// ---------------- k4: per-h MFMA GEMM  o[i][sc] = W[h] (384x384) x vT[h]^T (384x8192) ----------------
__global__ __launch_bounds__(256) void k4_mfma(
    const unsigned short* __restrict__ wbf, const unsigned short* __restrict__ vT,
    unsigned short* __restrict__ ob)
{
    __shared__ unsigned short Al[128 * 32];
    __shared__ unsigned short Bl[128 * 32];
    const int tid  = threadIdx.x;
    const int wid  = tid >> 6, lane = tid & 63;
    const int wm   = wid >> 1, wn = wid & 1;
    const int h    = blockIdx.z;
    const int i0   = blockIdx.y * 128;
    const int n0   = blockIdx.x * 128;
    const unsigned short* Ag = wbf + (size_t)h * NN * NN;
    const unsigned short* Bg = vT  + (size_t)h * 8192 * NN;

    f32x4 acc[4][4] = {};

    const int lrow = lane >> 2, lchunk = lane & 3;
    for (int k0 = 0; k0 < NN; k0 += 32) {
        #pragma unroll
        for (int q = 0; q < 2; q++) {
            int issue = wid * 2 + q;
            int r = issue * 16 + lrow;
            gload_lds16(Ag + (size_t)(i0 + r) * NN + k0 + lchunk * 8,
                        (void*)((char*)Al + issue * 1024));
            gload_lds16(Bg + (size_t)(n0 + r) * NN + k0 + lchunk * 8,
                        (void*)((char*)Bl + issue * 1024));
        }
        __syncthreads();

        short8v a[4], b[4];
        #pragma unroll
        for (int mi = 0; mi < 4; mi++)
            a[mi] = *(const short8v*)&Al[(wm * 64 + mi * 16 + (lane & 15)) * 32 + (lane >> 4) * 8];
        #pragma unroll
        for (int ni = 0; ni < 4; ni++)
            b[ni] = *(const short8v*)&Bl[(wn * 64 + ni * 16 + (lane & 15)) * 32 + (lane >> 4) * 8];
        #pragma unroll
        for (int mi = 0; mi < 4; mi++)
            #pragma unroll
            for (int ni = 0; ni < 4; ni++)
                acc[mi][ni] = __builtin_amdgcn_mfma_f32_16x16x32_bf16(a[mi], b[ni], acc[mi][ni], 0, 0, 0);
        __syncthreads();
    }

    #pragma unroll
    for (int mi = 0; mi < 4; mi++) {
        const int ibase = i0 + wm * 64 + mi * 16 + ((lane >> 4) << 2);
        #pragma unroll
        for (int ni = 0; ni < 4; ni++) {
            const int n = n0 + wn * 64 + ni * 16 + (lane & 15);
            const int s = n >> 5, c = n & 31;
            #pragma unroll
            for (int r = 0; r < 4; r++)
                ob[((size_t)s * NN + (ibase + r)) * HC + (h << 5) + c] = f2bf(acc[mi][ni][r]);
        }
    }
}

// ---------------- k5: out[98304,64] = (o .* g)[98304,256] @ w_out[256,64]  via MFMA ----------------
__global__ __launch_bounds__(256) void k5_mfma(
    const unsigned short* __restrict__ ob, const unsigned short* __restrict__ g,
    const float* __restrict__ w_out, float* __restrict__ out)
{
    __shared__ unsigned short WT[64 * 256];   // w_out^T bf16, swizzled: idx ^ ((c&7)<<3)
    const int tid = threadIdx.x, wid = tid >> 6, lane = tid & 63;
    #pragma unroll
    for (int e = 0; e < 16; e++) {
        int fidx = (tid + e * 256) * 4;
        float4 w4 = *(const float4*)&w_out[fidx];
        int k = fidx >> 6, c0 = fidx & 63;
        float wv[4] = {w4.x, w4.y, w4.z, w4.w};
        #pragma unroll
        for (int q = 0; q < 4; q++) {
            int c = c0 + q;
            WT[(((c << 8) + k)) ^ ((c & 7) << 3)] = f2bf(wv[q]);
        }
    }
    __syncthreads();

    const size_t rowbase = (size_t)blockIdx.x * 64 + wid * 16;
    const int arow = lane & 15, achunk = lane >> 4;
    const unsigned short* op = ob + (rowbase + arow) * HC + achunk * 8;
    const unsigned short* gp = g  + (rowbase + arow) * HC + achunk * 8;

    f32x4 acc[4] = {};
    #pragma unroll
    for (int ks = 0; ks < 8; ks++) {
        ushort8v o8 = *(const ushort8v*)(op + ks * 32);
        ushort8v g8 = *(const ushort8v*)(gp + ks * 32);
        short8v a;
        #pragma unroll
        for (int q = 0; q < 8; q++)
            a[q] = (short)f2bf(bf2f(o8[q]) * bf2f(g8[q]));
        #pragma unroll
        for (int nf = 0; nf < 4; nf++) {
            const int c = nf * 16 + arow;
            short8v b = *(const short8v*)&WT[(((c << 8) + ks * 32 + achunk * 8)) ^ ((c & 7) << 3)];
            acc[nf] = __builtin_amdgcn_mfma_f32_16x16x32_bf16(a, b, acc[nf], 0, 0, 0);
        }
    }
    #pragma unroll
    for (int nf = 0; nf < 4; nf++)
        #pragma unroll
        for (int r = 0; r < 4; r++)
            out[(rowbase + achunk * 4 + r) * CM + nf * 16 + arow] = acc[nf][r];
}

extern "C" void kernel_launch(void* const* d_in, const int* in_sizes, int n_in,
                              void* d_out, int out_size, void* d_ws, size_t ws_size,
                              hipStream_t stream)
{
    const float* m      = (const float*)d_in[0];
    const float* z      = (const float*)d_in[1];
    const unsigned int* mask_raw = (const unsigned int*)d_in[2];
    const float* ln_m_w = (const float*)d_in[3];
    const float* ln_m_b = (const float*)d_in[4];
    const float* ln_z_w = (const float*)d_in[5];
    const float* ln_z_b = (const float*)d_in[6];
    const float* w_v    = (const float*)d_in[7];
    const float* w_b    = (const float*)d_in[8];
    const float* w_g    = (const float*)d_in[9];
    const float* w_out  = (const float*)d_in[10];
    float* out = (float*)d_out;

    // ws: mterm f32[384] | wbl bf16[1179648] | vT bf16[NV] | g bf16[NV] | ob bf16[NV] | BTg bf16[32768]
    float* mterm = (float*)d_ws;
    unsigned short* wbl = (unsigned short*)(mterm + 384);
    unsigned short* vT  = wbl + 1179648;
    unsigned short* g   = vT + NV;
    unsigned short* ob  = g + NV;
    unsigned short* BTg = ob + NV;
    unsigned short* mln = ob;            // alias: dead before k4 writes ob

    k0_mask<<<1, 384, 0, stream>>>(mask_raw, mterm);
    k1a_stageB<<<128, 256, 0, stream>>>(w_v, w_g, BTg);
    k1n_ln<<<1536, 256, 0, stream>>>(m, ln_m_w, ln_m_b, mln);
    k1b_vg<<<dim3(1536, 2), 256, 0, stream>>>(BTg, mln, vT, g);
    k2_lnz_b<<<36864, 256, 0, stream>>>(z, ln_z_w, ln_z_b, w_b, mterm, wbl);
    k3_softmax<<<768, 256, 0, stream>>>(wbl);
    k4_mfma<<<dim3(64, 3, 8), 256, 0, stream>>>(wbl, vT, ob);
    k5_mfma<<<1536, 256, 0, stream>>>(ob, g, w_out, out);
}

// Round 9
// 141.633 us; speedup vs baseline: 4.4855x; 1.5064x over previous
//
#include <hip/hip_runtime.h>
#include <math.h>

// MSAPairWeightedAveraging — round 8: k2 -> algebraic LN-fold + MFMA projection.
// S=256, N=384, C_M=64, C_Z=128, C=32, H=8, H*C=256.
// ws: mterm f32[384] | wbl bf16[8,384,384] | vT bf16[8,8192,384] | g bf16[98304,256]
//     | ob bf16[98304,256] (aliased as mln pre-k4) | BTg bf16[512,64] | w2bf bf16[16,128] | consts f32[32]

#define SS 256
#define NN 384
#define CM 64
#define CZ 128
#define HH 8
#define HC 256
#define NV 25165824   // S*N*HC

typedef __attribute__((ext_vector_type(8))) short short8v;
typedef __attribute__((ext_vector_type(8))) unsigned short ushort8v;
typedef __attribute__((ext_vector_type(4))) float f32x4;

static __device__ __forceinline__ float bf2f(unsigned short u) {
    union { unsigned int i; float f; } x; x.i = ((unsigned int)u) << 16; return x.f;
}
static __device__ __forceinline__ unsigned short f2bf(float f) {
    union { float f; unsigned int i; } x; x.f = f;
    unsigned int r = x.i + 0x7FFFu + ((x.i >> 16) & 1u);   // RNE
    return (unsigned short)(r >> 16);
}
static __device__ __forceinline__ void gload_lds16(const void* g, void* l) {
    __builtin_amdgcn_global_load_lds((const __attribute__((address_space(1))) void*)g,
                                     (__attribute__((address_space(3))) void*)l, 16, 0, 0);
}

// ---------------- k0: decode single_mask (uint8 / int32 / float32) -> mterm[384] ----------------
__global__ __launch_bounds__(384) void k0_mask(const unsigned int* __restrict__ mu,
                                               float* __restrict__ mterm)
{
    __shared__ int byteLayout;
    if (threadIdx.x == 0) byteLayout = 0;
    __syncthreads();
    if (threadIdx.x < 96) {
        unsigned int u = mu[threadIdx.x];
        if (u != 0u && u != 1u && u != 0x3F800000u) atomicOr(&byteLayout, 1);
    }
    __syncthreads();
    const int j = threadIdx.x;
    int val;
    if (byteLayout) val = ((const unsigned char*)mu)[j];
    else            val = (mu[j] != 0u);
    mterm[j] = val ? 0.0f : -1e9f;
}

// ---------------- k1a: transpose [w_v|w_g] fp32 [64][256] -> BTg bf16 [512 cols][64 k], swizzled ----------------
__global__ __launch_bounds__(256) void k1a_stageB(
    const float* __restrict__ w_v, const float* __restrict__ w_g,
    unsigned short* __restrict__ BTg)
{
    const int col = blockIdx.x * 4 + (threadIdx.x >> 6);
    const int k   = threadIdx.x & 63;
    float w = (col < 256) ? w_v[k * 256 + col] : w_g[k * 256 + (col - 256)];
    BTg[col * 64 + (k ^ ((col & 7) << 3))] = f2bf(w);
}

// ---------------- k2a: fold LN into w_b -> w2bf[16 cols][128 k] bf16, consts[32] f32 ----------------
__global__ __launch_bounds__(128) void k2a_stageW(
    const float* __restrict__ lnw, const float* __restrict__ lnb, const float* __restrict__ w_b,
    unsigned short* __restrict__ w2bf, float* __restrict__ consts)
{
    __shared__ float pA[128][8], pB[128][8];
    const int c = threadIdx.x;
    float lw = lnw[c], lb = lnb[c];
    float4 wb0 = *(const float4*)&w_b[c * 8];
    float4 wb1 = *(const float4*)&w_b[c * 8 + 4];
    float wv[8] = {wb0.x, wb0.y, wb0.z, wb0.w, wb1.x, wb1.y, wb1.z, wb1.w};
    #pragma unroll
    for (int h = 0; h < 8; h++) {
        w2bf[h * CZ + c]       = f2bf(lw * wv[h]);
        w2bf[(8 + h) * CZ + c] = 0;
        pA[c][h] = lw * wv[h];
        pB[c][h] = lb * wv[h];
    }
    __syncthreads();
    if (c < 8) {
        float A = 0.f, B = 0.f;
        for (int q = 0; q < 128; q++) { A += pA[q][c]; B += pB[q][c]; }
        consts[c] = A; consts[16 + c] = B;
        consts[8 + c] = 0.f; consts[24 + c] = 0.f;
    }
}

// ---------------- k1n: LN(m) -> mln bf16 [98304][64], pre-swizzled within rows ----------------
__global__ __launch_bounds__(256) void k1n_ln(
    const float* __restrict__ m, const float* __restrict__ lnw, const float* __restrict__ lnb,
    unsigned short* __restrict__ mln)
{
    const int tid = threadIdx.x, wid = tid >> 6, lane = tid & 63;
    const int rowBase = blockIdx.x * 64 + wid * 16;
    const float lw = lnw[lane], lb = lnb[lane];
    #pragma unroll 4
    for (int rr = 0; rr < 16; rr++) {
        int row = rowBase + rr;
        float x = m[(size_t)row * CM + lane];
        float s1 = x, s2 = x * x;
        #pragma unroll
        for (int off = 32; off; off >>= 1) {
            s1 += __shfl_xor(s1, off);
            s2 += __shfl_xor(s2, off);
        }
        float mu  = s1 * (1.0f / CM);
        float var = s2 * (1.0f / CM) - mu * mu;
        float y = (x - mu) * rsqrtf(var + 1e-5f) * lw + lb;
        mln[(size_t)row * CM + (lane ^ ((row & 7) << 3))] = f2bf(y);
    }
}

// ---------------- k1b: GEMM mln[64k] x {w_v,w_g}[64k,256] per 64-row tile ----------------
__global__ __launch_bounds__(256) void k1b_vg(
    const unsigned short* __restrict__ BTg, const unsigned short* __restrict__ mln,
    unsigned short* __restrict__ vT, unsigned short* __restrict__ gout)
{
    __shared__ unsigned short Wl[16384];  // [256 cols][64 k] swizzled
    __shared__ unsigned short Al[4096];   // [64 rows][64 k] swizzled
    const int tid = threadIdx.x, wid = tid >> 6, lane = tid & 63;
    const int rl = lane & 15, kc = lane >> 4;
    const int rowBase = blockIdx.x * 64;
    const int s = rowBase / NN, j0 = rowBase - s * NN;
    const int fam = blockIdx.y;

    #pragma unroll
    for (int it = 0; it < 8; it++) {
        int eoff = (wid * 8 + it) * 512;
        gload_lds16(BTg + fam * 16384 + eoff + lane * 8, (void*)((char*)Wl + eoff * 2));
    }
    #pragma unroll
    for (int it = 0; it < 2; it++) {
        int eoff = (wid * 2 + it) * 512;
        gload_lds16(mln + (size_t)rowBase * CM + eoff + lane * 8, (void*)((char*)Al + eoff * 2));
    }
    __syncthreads();

    f32x4 acc[4][4] = {};
    #pragma unroll
    for (int ks = 0; ks < 2; ks++) {
        short8v wf[4], al[4];
        #pragma unroll
        for (int q = 0; q < 4; q++) {
            int col = wid * 64 + q * 16 + rl;
            wf[q] = *(const short8v*)&Wl[(col * 64 + ks * 32 + kc * 8) ^ ((col & 7) << 3)];
            int row = q * 16 + rl;
            al[q] = *(const short8v*)&Al[(row * 64 + ks * 32 + kc * 8) ^ ((row & 7) << 3)];
        }
        if (fam == 0) {
            #pragma unroll
            for (int mi = 0; mi < 4; mi++)
                #pragma unroll
                for (int nf = 0; nf < 4; nf++)
                    acc[mi][nf] = __builtin_amdgcn_mfma_f32_16x16x32_bf16(wf[mi], al[nf], acc[mi][nf], 0, 0, 0);
        } else {
            #pragma unroll
            for (int mi = 0; mi < 4; mi++)
                #pragma unroll
                for (int nf = 0; nf < 4; nf++)
                    acc[mi][nf] = __builtin_amdgcn_mfma_f32_16x16x32_bf16(al[mi], wf[nf], acc[mi][nf], 0, 0, 0);
        }
    }

    if (fam == 0) {
        #pragma unroll
        for (int mi = 0; mi < 4; mi++)
            #pragma unroll
            for (int nf = 0; nf < 4; nf++) {
                int j = j0 + nf * 16 + rl;
                #pragma unroll
                for (int r = 0; r < 4; r++) {
                    int hc = wid * 64 + mi * 16 + kc * 4 + r;
                    size_t vrow = (size_t)((hc >> 5) * 8192 + s * 32 + (hc & 31));
                    vT[vrow * NN + j] = f2bf(acc[mi][nf][r]);
                }
            }
    } else {
        #pragma unroll
        for (int mi = 0; mi < 4; mi++)
            #pragma unroll
            for (int nf = 0; nf < 4; nf++) {
                int hc = wid * 64 + nf * 16 + rl;
                #pragma unroll
                for (int r = 0; r < 4; r++) {
                    int row = rowBase + mi * 16 + kc * 4 + r;
                    float sg = 1.0f / (1.0f + expf(-acc[mi][nf][r]));
                    gout[(size_t)row * HC + hc] = f2bf(sg);
                }
            }
    }
}

// ---------------- k2: MFMA projection: b = rstd*(z@W2) - rstd*mu*A + B + mask ----------------
// 4 waves x 16 rows per block; fp32 LN stats; A-frags from fp32 z in regs; B-frags from global.
__global__ __launch_bounds__(256) void k2_mfma(
    const float* __restrict__ z, const unsigned short* __restrict__ w2bf,
    const float* __restrict__ consts, const float* __restrict__ mterm,
    unsigned short* __restrict__ wbl)
{
    __shared__ float st[4][16][2];
    const int tid = threadIdx.x, wid = tid >> 6, lane = tid & 63;
    const int rl = lane & 15, kc = lane >> 4;
    const int rowBase = blockIdx.x * 64 + wid * 16;
    const int i = rowBase / NN, j0 = rowBase - i * NN;   // 16-row group never straddles i
    const float* zr = z + (size_t)(rowBase + rl) * CZ + kc * 8;

    float s1 = 0.f, s2 = 0.f;
    short8v af[4];
    #pragma unroll
    for (int ks = 0; ks < 4; ks++) {
        float4 z0 = *(const float4*)(zr + ks * 32);
        float4 z1 = *(const float4*)(zr + ks * 32 + 4);
        float zz[8] = {z0.x, z0.y, z0.z, z0.w, z1.x, z1.y, z1.z, z1.w};
        short8v a;
        #pragma unroll
        for (int q = 0; q < 8; q++) {
            s1 += zz[q];
            s2 += zz[q] * zz[q];
            a[q] = (short)f2bf(zz[q]);
        }
        af[ks] = a;
    }
    // reduce stats across the 4 lanes sharing a row (lanes r, r+16, r+32, r+48)
    s1 += __shfl_xor(s1, 16); s2 += __shfl_xor(s2, 16);
    s1 += __shfl_xor(s1, 32); s2 += __shfl_xor(s2, 32);
    if (kc == 0) { st[wid][rl][0] = s1; st[wid][rl][1] = s2; }

    f32x4 acc = {};
    #pragma unroll
    for (int ks = 0; ks < 4; ks++) {
        short8v b = *(const short8v*)&w2bf[rl * CZ + ks * 32 + kc * 8];
        acc = __builtin_amdgcn_mfma_f32_16x16x32_bf16(af[ks], b, acc, 0, 0, 0);
    }
    __syncthreads();

    const float Ah = consts[rl], Bh = consts[16 + rl];
    unsigned short pv[4];
    #pragma unroll
    for (int reg = 0; reg < 4; reg++) {
        int r = 4 * kc + reg;
        float S1 = st[wid][r][0], S2 = st[wid][r][1];
        float mu   = S1 * (1.0f / CZ);
        float var  = S2 * (1.0f / CZ) - mu * mu;
        float rstd = rsqrtf(var + 1e-5f);
        float b = rstd * acc[reg] - rstd * mu * Ah + Bh + mterm[j0 + r];
        pv[reg] = f2bf(b);
    }
    if (rl < 8) {
        ushort4 o4 = {pv[0], pv[1], pv[2], pv[3]};
        *(ushort4*)&wbl[((size_t)rl * NN + i) * NN + j0 + 4 * kc] = o4;
    }
}

// ---------------- k3: softmax over j, bf16 in place on wbl[h][i][:] ----------------
__global__ __launch_bounds__(256) void k3_softmax(unsigned short* __restrict__ wbl)
{
    const int tid = threadIdx.x, wave = tid >> 6, lane = tid & 63;
    const int row = blockIdx.x * 4 + wave;   // = h*384 + i
    unsigned short* p = wbl + (size_t)row * NN;
    float x[6];
    float mx = -1e30f;
    #pragma unroll
    for (int e = 0; e < 6; e++) { x[e] = bf2f(p[lane + e * 64]); mx = fmaxf(mx, x[e]); }
    #pragma unroll
    for (int off = 32; off; off >>= 1) mx = fmaxf(mx, __shfl_xor(mx, off));
    float sum = 0.f;
    #pragma unroll
    for (int e = 0; e < 6; e++) { x[e] = expf(x[e] - mx); sum += x[e]; }
    #pragma unroll
    for (int off = 32; off; off >>= 1) sum += __shfl_xor(sum, off);
    float inv = 1.0f / sum;
    #pragma unroll
    for (int e = 0; e < 6; e++) p[lane + e * 64] = f2bf(x[e] * inv);
}

// ---------------- k4: per-h MFMA GEMM  o[i][sc] = W[h] (384x384) x vT[h]^T (384x8192) ----------------
__global__ __launch_bounds__(256) void k4_mfma(
    const unsigned short* __restrict__ wbf, const unsigned short* __restrict__ vT,
    unsigned short* __restrict__ ob)
{
    __shared__ unsigned short Al[128 * 32];
    __shared__ unsigned short Bl[128 * 32];
    const int tid  = threadIdx.x;
    const int wid  = tid >> 6, lane = tid & 63;
    const int wm   = wid >> 1, wn = wid & 1;
    const int h    = blockIdx.z;
    const int i0   = blockIdx.y * 128;
    const int n0   = blockIdx.x * 128;
    const unsigned short* Ag = wbf + (size_t)h * NN * NN;
    const unsigned short* Bg = vT  + (size_t)h * 8192 * NN;

    f32x4 acc[4][4] = {};

    const int lrow = lane >> 2, lchunk = lane & 3;
    for (int k0 = 0; k0 < NN; k0 += 32) {
        #pragma unroll
        for (int q = 0; q < 2; q++) {
            int issue = wid * 2 + q;
            int r = issue * 16 + lrow;
            gload_lds16(Ag + (size_t)(i0 + r) * NN + k0 + lchunk * 8,
                        (void*)((char*)Al + issue * 1024));
            gload_lds16(Bg + (size_t)(n0 + r) * NN + k0 + lchunk * 8,
                        (void*)((char*)Bl + issue * 1024));
        }
        __syncthreads();

        short8v a[4], b[4];
        #pragma unroll
        for (int mi = 0; mi < 4; mi++)
            a[mi] = *(const short8v*)&Al[(wm * 64 + mi * 16 + (lane & 15)) * 32 + (lane >> 4) * 8];
        #pragma unroll
        for (int ni = 0; ni < 4; ni++)
            b[ni] = *(const short8v*)&Bl[(wn * 64 + ni * 16 + (lane & 15)) * 32 + (lane >> 4) * 8];
        #pragma unroll
        for (int mi = 0; mi < 4; mi++)
            #pragma unroll
            for (int ni = 0; ni < 4; ni++)
                acc[mi][ni] = __builtin_amdgcn_mfma_f32_16x16x32_bf16(a[mi], b[ni], acc[mi][ni], 0, 0, 0);
        __syncthreads();
    }

    #pragma unroll
    for (int mi = 0; mi < 4; mi++) {
        const int ibase = i0 + wm * 64 + mi * 16 + ((lane >> 4) << 2);
        #pragma unroll
        for (int ni = 0; ni < 4; ni++) {
            const int n = n0 + wn * 64 + ni * 16 + (lane & 15);
            const int s = n >> 5, c = n & 31;
            #pragma unroll
            for (int r = 0; r < 4; r++)
                ob[((size_t)s * NN + (ibase + r)) * HC + (h << 5) + c] = f2bf(acc[mi][ni][r]);
        }
    }
}

// ---------------- k5: out[98304,64] = (o .* g)[98304,256] @ w_out[256,64]  via MFMA ----------------
__global__ __launch_bounds__(256) void k5_mfma(
    const unsigned short* __restrict__ ob, const unsigned short* __restrict__ g,
    const float* __restrict__ w_out, float* __restrict__ out)
{
    __shared__ unsigned short WT[64 * 256];   // w_out^T bf16, swizzled: idx ^ ((c&7)<<3)
    const int tid = threadIdx.x, wid = tid >> 6, lane = tid & 63;
    #pragma unroll
    for (int e = 0; e < 16; e++) {
        int fidx = (tid + e * 256) * 4;
        float4 w4 = *(const float4*)&w_out[fidx];
        int k = fidx >> 6, c0 = fidx & 63;
        float wv[4] = {w4.x, w4.y, w4.z, w4.w};
        #pragma unroll
        for (int q = 0; q < 4; q++) {
            int c = c0 + q;
            WT[(((c << 8) + k)) ^ ((c & 7) << 3)] = f2bf(wv[q]);
        }
    }
    __syncthreads();

    const size_t rowbase = (size_t)blockIdx.x * 64 + wid * 16;
    const int arow = lane & 15, achunk = lane >> 4;
    const unsigned short* op = ob + (rowbase + arow) * HC + achunk * 8;
    const unsigned short* gp = g  + (rowbase + arow) * HC + achunk * 8;

    f32x4 acc[4] = {};
    #pragma unroll
    for (int ks = 0; ks < 8; ks++) {
        ushort8v o8 = *(const ushort8v*)(op + ks * 32);
        ushort8v g8 = *(const ushort8v*)(gp + ks * 32);
        short8v a;
        #pragma unroll
        for (int q = 0; q < 8; q++)
            a[q] = (short)f2bf(bf2f(o8[q]) * bf2f(g8[q]));
        #pragma unroll
        for (int nf = 0; nf < 4; nf++) {
            const int c = nf * 16 + arow;
            short8v b = *(const short8v*)&WT[(((c << 8) + ks * 32 + achunk * 8)) ^ ((c & 7) << 3)];
            acc[nf] = __builtin_amdgcn_mfma_f32_16x16x32_bf16(a, b, acc[nf], 0, 0, 0);
        }
    }
    #pragma unroll
    for (int nf = 0; nf < 4; nf++)
        #pragma unroll
        for (int r = 0; r < 4; r++)
            out[(rowbase + achunk * 4 + r) * CM + nf * 16 + arow] = acc[nf][r];
}

extern "C" void kernel_launch(void* const* d_in, const int* in_sizes, int n_in,
                              void* d_out, int out_size, void* d_ws, size_t ws_size,
                              hipStream_t stream)
{
    const float* m      = (const float*)d_in[0];
    const float* z      = (const float*)d_in[1];
    const unsigned int* mask_raw = (const unsigned int*)d_in[2];
    const float* ln_m_w = (const float*)d_in[3];
    const float* ln_m_b = (const float*)d_in[4];
    const float* ln_z_w = (const float*)d_in[5];
    const float* ln_z_b = (const float*)d_in[6];
    const float* w_v    = (const float*)d_in[7];
    const float* w_b    = (const float*)d_in[8];
    const float* w_g    = (const float*)d_in[9];
    const float* w_out  = (const float*)d_in[10];
    float* out = (float*)d_out;

    // ws layout
    float* mterm = (float*)d_ws;
    unsigned short* wbl = (unsigned short*)(mterm + 384);
    unsigned short* vT  = wbl + 1179648;
    unsigned short* g   = vT + NV;
    unsigned short* ob  = g + NV;
    unsigned short* BTg = ob + NV;             // [512][64]
    unsigned short* w2bf = BTg + 32768;        // [16][128]
    float* consts = (float*)(w2bf + 2048);     // [32]
    unsigned short* mln = ob;                  // alias: dead before k4 writes ob

    k0_mask<<<1, 384, 0, stream>>>(mask_raw, mterm);
    k1a_stageB<<<128, 256, 0, stream>>>(w_v, w_g, BTg);
    k2a_stageW<<<1, 128, 0, stream>>>(ln_z_w, ln_z_b, w_b, w2bf, consts);
    k1n_ln<<<1536, 256, 0, stream>>>(m, ln_m_w, ln_m_b, mln);
    k1b_vg<<<dim3(1536, 2), 256, 0, stream>>>(BTg, mln, vT, g);
    k2_mfma<<<2304, 256, 0, stream>>>(z, w2bf, consts, mterm, wbl);
    k3_softmax<<<768, 256, 0, stream>>>(wbl);
    k4_mfma<<<dim3(64, 3, 8), 256, 0, stream>>>(wbl, vT, ob);
    k5_mfma<<<1536, 256, 0, stream>>>(ob, g, w_out, out);
}